// Round 15
// baseline (128.750 us; speedup 1.0000x reference)
//
#include <hip/hip_runtime.h>

#define BATCH   32768
#define SD      256
#define LD      64
#define HDIM    64
#define NEMB    2048
#define REFINE_THR_Q 5e-4f   // gap in q-units; s-gap = 2*q-gap -> 1e-3 effective

typedef short  short8 __attribute__((ext_vector_type(8)));
typedef float  f32x4  __attribute__((ext_vector_type(4)));

__device__ __forceinline__ unsigned short f2bf(float f) {
    unsigned int u = __float_as_uint(f);
    u = (u + 0x7FFFu + ((u >> 16) & 1u)) >> 16;
    return (unsigned short)u;
}
__device__ __forceinline__ float bf2f(unsigned short h) {
    return __uint_as_float(((unsigned int)h) << 16);
}

// ---------------------------------------------------------------------------
// K0 (merged): b 0..7   codebook e2q + 2-way split eh/el
//              b 8..23  dec_w1 2-way split transposed [j][k]
//              b 24..87 dec_w2 2-way split transposed [j][k]
//              b 88..151 enc_w1 3-way split transposed [j(64)][k(256)]
//              b 152..167 enc_w2 3-way split transposed [j(64)][k(64)]
// ---------------------------------------------------------------------------
__global__ __launch_bounds__(256) void k0_all(const float* __restrict__ emb,
                                              const float* __restrict__ dw1,
                                              const float* __restrict__ dw2,
                                              const float* __restrict__ ew1,
                                              const float* __restrict__ ew2,
                                              float* __restrict__ e2q,
                                              unsigned short* __restrict__ eh,
                                              unsigned short* __restrict__ el,
                                              unsigned short* __restrict__ w1h,
                                              unsigned short* __restrict__ w1l,
                                              unsigned short* __restrict__ w2h,
                                              unsigned short* __restrict__ w2l,
                                              unsigned short* __restrict__ w1eh,
                                              unsigned short* __restrict__ w1em,
                                              unsigned short* __restrict__ w1el,
                                              unsigned short* __restrict__ w2eh,
                                              unsigned short* __restrict__ w2em,
                                              unsigned short* __restrict__ w2el) {
    int b = blockIdx.x;
    int t = threadIdx.x;
    if (b < 8) {
        int k = b * 256 + t;
        const float* er = emb + (size_t)k * LD;
        unsigned short hrow[LD], lrow[LD];
        float s = 0.f;
#pragma unroll
        for (int q = 0; q < LD; ++q) {
            float v = er[q];
            s += v * v;
            unsigned short h = f2bf(v);
            hrow[q] = h;
            lrow[q] = f2bf(v - bf2f(h));
        }
        e2q[k] = -0.5f * s;
        short8* dh = (short8*)(eh + (size_t)k * LD);
        short8* dl = (short8*)(el + (size_t)k * LD);
#pragma unroll
        for (int q = 0; q < 8; ++q) {
            dh[q] = *(short8*)&hrow[q * 8];
            dl[q] = *(short8*)&lrow[q * 8];
        }
    } else if (b < 24) {
        int e = (b - 8) * 256 + t;
        int j = e >> 6, k = e & 63;
        float v = dw1[k * HDIM + j];
        unsigned short h = f2bf(v);
        w1h[e] = h; w1l[e] = f2bf(v - bf2f(h));
    } else if (b < 88) {
        int e = (b - 24) * 256 + t;
        int j = e >> 6, k = e & 63;
        float v = dw2[k * SD + j];
        unsigned short h = f2bf(v);
        w2h[e] = h; w2l[e] = f2bf(v - bf2f(h));
    } else if (b < 152) {
        int e = (b - 88) * 256 + t;      // [j][k]: j = e>>8, k = e&255
        int j = e >> 8, k = e & 255;
        float v = ew1[k * HDIM + j];
        unsigned short h = f2bf(v);
        float r1 = v - bf2f(h);
        unsigned short m = f2bf(r1);
        float r2 = r1 - bf2f(m);
        w1eh[e] = h; w1em[e] = m; w1el[e] = f2bf(r2);
    } else {
        int e = (b - 152) * 256 + t;     // [j][k]: j = e>>6, k = e&63
        int j = e >> 6, k = e & 63;
        float v = ew2[k * LD + j];
        unsigned short h = f2bf(v);
        float r1 = v - bf2f(h);
        unsigned short m = f2bf(r1);
        float r2 = r1 - bf2f(m);
        w2eh[e] = h; w2em[e] = m; w2el[e] = f2bf(r2);
    }
}

// ---------------------------------------------------------------------------
// ENC v5 (MFMA, 6-term split = f32-equivalent precision):
// Mirrors proven k_dec structure. 512 blocks x 256 thr (4 waves x 16 rows).
// L1: K=256, A = x rows split 3-way in-register; B = pre-split transposed
// w1 [j][k] (L2-resident); 8 kt x 4 jt x 6 MFMA, bias via C-init.
// hd handoff via per-wave LDS stripe [16][68]; L2 same pattern (2 kt).
// Output z_e f32 + 2-way split zh/zl for k2.
// ---------------------------------------------------------------------------
#define MF(Afr, Bfr, C) __builtin_amdgcn_mfma_f32_16x16x32_bf16(Afr, Bfr, C, 0, 0, 0)

__global__ __launch_bounds__(256, 2) void k_enc(const float* __restrict__ x,
                                                const unsigned short* __restrict__ w1eh,
                                                const unsigned short* __restrict__ w1em,
                                                const unsigned short* __restrict__ w1el,
                                                const float* __restrict__ b1,
                                                const unsigned short* __restrict__ w2eh,
                                                const unsigned short* __restrict__ w2em,
                                                const unsigned short* __restrict__ w2el,
                                                const float* __restrict__ b2,
                                                float* __restrict__ zOut,
                                                unsigned short* __restrict__ zh,
                                                unsigned short* __restrict__ zl) {
    __shared__ float hds[4][16 * 68];
    int tid  = threadIdx.x;
    int lane = tid & 63;
    int w    = tid >> 6;
    int lo   = lane & 15;
    int hi   = lane >> 4;
    int rb   = blockIdx.x * 64 + w * 16;
    int row  = rb + lo;

    // ---- layer 1: c1[jt] = x @ w1 + b1 over K=256
    f32x4 c1[4];
#pragma unroll
    for (int jt = 0; jt < 4; ++jt) {
        float bj = b1[jt * 16 + lo];
        f32x4 c = {bj, bj, bj, bj};
        c1[jt] = c;
    }

#pragma unroll
    for (int kt = 0; kt < 8; ++kt) {
        const float* xp = x + (size_t)row * SD + kt * 32 + hi * 8;
        float4 a4 = *(const float4*)xp;
        float4 b4 = *(const float4*)(xp + 4);
        float v[8] = {a4.x, a4.y, a4.z, a4.w, b4.x, b4.y, b4.z, b4.w};
        unsigned short sh[8], sm[8], sl[8];
#pragma unroll
        for (int q = 0; q < 8; ++q) {
            unsigned short h = f2bf(v[q]);
            float r1 = v[q] - bf2f(h);
            unsigned short m = f2bf(r1);
            float r2 = r1 - bf2f(m);
            sh[q] = h; sm[q] = m; sl[q] = f2bf(r2);
        }
        short8 ah = *(short8*)sh, am = *(short8*)sm, al = *(short8*)sl;
#pragma unroll
        for (int jt = 0; jt < 4; ++jt) {
            size_t wo = (size_t)(jt * 16 + lo) * SD + kt * 32 + hi * 8;
            short8 bh8 = *(const short8*)(w1eh + wo);
            short8 bm8 = *(const short8*)(w1em + wo);
            short8 bl8 = *(const short8*)(w1el + wo);
            f32x4 c = c1[jt];
            c = MF(al, bh8, c);      // small terms first
            c = MF(am, bm8, c);
            c = MF(ah, bl8, c);
            c = MF(am, bh8, c);
            c = MF(ah, bm8, c);
            c = MF(ah, bh8, c);
            c1[jt] = c;
        }
    }
    // relu -> per-wave LDS stripe (C layout: row=hi*4+r, col=jt*16+lo)
#pragma unroll
    for (int jt = 0; jt < 4; ++jt)
#pragma unroll
        for (int r = 0; r < 4; ++r)
            hds[w][(hi * 4 + r) * 68 + jt * 16 + lo] = fmaxf(c1[jt][r], 0.f);
    __syncthreads();

    // ---- layer 2: z = hd @ w2 + b2 over K=64 (A-frag: row=lo, k=kt*32+hi*8)
    f32x4 c2[4];
#pragma unroll
    for (int jt = 0; jt < 4; ++jt) {
        float bj = b2[jt * 16 + lo];
        f32x4 c = {bj, bj, bj, bj};
        c2[jt] = c;
    }
#pragma unroll
    for (int kt = 0; kt < 2; ++kt) {
        float4 a4 = *(const float4*)&hds[w][lo * 68 + kt * 32 + hi * 8];
        float4 b4 = *(const float4*)&hds[w][lo * 68 + kt * 32 + hi * 8 + 4];
        float v[8] = {a4.x, a4.y, a4.z, a4.w, b4.x, b4.y, b4.z, b4.w};
        unsigned short sh[8], sm[8], sl[8];
#pragma unroll
        for (int q = 0; q < 8; ++q) {
            unsigned short h = f2bf(v[q]);
            float r1 = v[q] - bf2f(h);
            unsigned short m = f2bf(r1);
            float r2 = r1 - bf2f(m);
            sh[q] = h; sm[q] = m; sl[q] = f2bf(r2);
        }
        short8 ah = *(short8*)sh, am = *(short8*)sm, al = *(short8*)sl;
#pragma unroll
        for (int jt = 0; jt < 4; ++jt) {
            size_t wo = (size_t)(jt * 16 + lo) * LD + kt * 32 + hi * 8;
            short8 bh8 = *(const short8*)(w2eh + wo);
            short8 bm8 = *(const short8*)(w2em + wo);
            short8 bl8 = *(const short8*)(w2el + wo);
            f32x4 c = c2[jt];
            c = MF(al, bh8, c);
            c = MF(am, bm8, c);
            c = MF(ah, bl8, c);
            c = MF(am, bh8, c);
            c = MF(ah, bm8, c);
            c = MF(ah, bh8, c);
            c2[jt] = c;
        }
    }
    // write z_e (f32) + 2-way split zh/zl; coalesced per 16-lane group
#pragma unroll
    for (int jt = 0; jt < 4; ++jt) {
#pragma unroll
        for (int r = 0; r < 4; ++r) {
            float z = c2[jt][r];
            size_t o = (size_t)(rb + hi * 4 + r) * LD + jt * 16 + lo;
            zOut[o] = z;
            unsigned short hb = f2bf(z);
            zh[o] = hb;
            zl[o] = f2bf(z - bf2f(hb));
        }
    }
}

// ---------------------------------------------------------------------------
// K2: MFMA split-bf16 screen (proven: slim tracker, 3-deep named prefetch)
// + FUSED exact-f64 rescan of this block's flagged rows (was k3).
// ---------------------------------------------------------------------------
#define K2_LOAD(P, t) do {                                                  \
    const unsigned short* ph_ = ehp + (size_t)(t) * 16 * LD;                \
    const unsigned short* pl_ = elp + (size_t)(t) * 16 * LD;                \
    P##a0 = *(const short8*)(ph_);                                          \
    P##a1 = *(const short8*)(ph_ + 32);                                     \
    P##a2 = *(const short8*)(pl_);                                          \
    P##a3 = *(const short8*)(pl_ + 32);                                     \
    P##e2 = *(const f32x4*)(e2q + cbase + (t) * 16 + hi * 4);               \
} while (0)

#define K2_COMP(P, t) do {                                                  \
    f32x4 acc_[4];                                                          \
    _Pragma("unroll")                                                       \
    for (int g = 0; g < 4; ++g) {                                           \
        f32x4 c_;                                                           \
        c_ = __builtin_amdgcn_mfma_f32_16x16x32_bf16(P##a0, bh[g][0], P##e2, 0, 0, 0); \
        c_ = __builtin_amdgcn_mfma_f32_16x16x32_bf16(P##a1, bh[g][1], c_, 0, 0, 0);    \
        c_ = __builtin_amdgcn_mfma_f32_16x16x32_bf16(P##a2, bh[g][0], c_, 0, 0, 0);    \
        c_ = __builtin_amdgcn_mfma_f32_16x16x32_bf16(P##a3, bh[g][1], c_, 0, 0, 0);    \
        c_ = __builtin_amdgcn_mfma_f32_16x16x32_bf16(P##a0, bl[g][0], c_, 0, 0, 0);    \
        c_ = __builtin_amdgcn_mfma_f32_16x16x32_bf16(P##a1, bl[g][1], c_, 0, 0, 0);    \
        acc_[g] = c_;                                                       \
    }                                                                       \
    _Pragma("unroll")                                                       \
    for (int g = 0; g < 4; ++g) {                                           \
        float m_ = fmaxf(fmaxf(acc_[g][0], acc_[g][1]),                     \
                         fmaxf(acc_[g][2], acc_[g][3]));                    \
        bool win_ = (m_ > bb[g]);                                           \
        qv[g] = win_ ? acc_[g] : qv[g];                                     \
        tt[g] = win_ ? (t) : tt[g];                                         \
        b2v[g] = fmaxf(b2v[g], fminf(bb[g], m_));                           \
        bb[g] = fmaxf(bb[g], m_);                                           \
    }                                                                       \
} while (0)

__global__ __launch_bounds__(256, 2) void k2_mfma(const unsigned short* __restrict__ zh,
                                                  const unsigned short* __restrict__ zl,
                                                  const unsigned short* __restrict__ eh,
                                                  const unsigned short* __restrict__ el,
                                                  const float* __restrict__ e2q,
                                                  const float* __restrict__ zE,
                                                  const float* __restrict__ emb,
                                                  int* __restrict__ idx) {
    int tid  = threadIdx.x;
    int lane = tid & 63;
    int w    = tid >> 6;
    int rb   = blockIdx.x * 64;
    int lo   = lane & 15;
    int hi   = lane >> 4;

    short8 bh[4][2], bl[4][2];
#pragma unroll
    for (int g = 0; g < 4; ++g) {
        size_t zo = (size_t)(rb + g * 16 + lo) * LD + hi * 8;
        bh[g][0] = *(const short8*)(zh + zo);
        bh[g][1] = *(const short8*)(zh + zo + 32);
        bl[g][0] = *(const short8*)(zl + zo);
        bl[g][1] = *(const short8*)(zl + zo + 32);
    }

    float bb[4], b2v[4];
    f32x4 qv[4];
    int   tt[4];
#pragma unroll
    for (int g = 0; g < 4; ++g) {
        bb[g] = -3.0e38f; b2v[g] = -3.0e38f; tt[g] = 0;
        qv[g][0] = qv[g][1] = qv[g][2] = qv[g][3] = -3.0e38f;
    }

    const int cbase = w * (NEMB / 4);
    const unsigned short* ehp = eh + (size_t)(cbase + lo) * LD + hi * 8;
    const unsigned short* elp = el + (size_t)(cbase + lo) * LD + hi * 8;

    short8 Aa0, Aa1, Aa2, Aa3; f32x4 Ae2;
    short8 Ba0, Ba1, Ba2, Ba3; f32x4 Be2;
    short8 Ca0, Ca1, Ca2, Ca3; f32x4 Ce2;

    K2_LOAD(A, 0);
    K2_LOAD(B, 1);
    K2_LOAD(C, 2);

    for (int tb = 0; tb < 27; tb += 3) {
        K2_COMP(A, tb);     K2_LOAD(A, tb + 3);
        K2_COMP(B, tb + 1); K2_LOAD(B, tb + 4);
        K2_COMP(C, tb + 2); K2_LOAD(C, tb + 5);
    }
    K2_COMP(A, 27); K2_LOAD(A, 30);
    K2_COMP(B, 28); K2_LOAD(B, 31);
    K2_COMP(C, 29);
    K2_COMP(A, 30);
    K2_COMP(B, 31);

    float ss[4];
    int   ii[4];
#pragma unroll
    for (int g = 0; g < 4; ++g) {
        float s0 = qv[g][0], s1 = qv[g][1], s2 = qv[g][2], s3 = qv[g][3];
        float M01 = fmaxf(s0, s1), L01 = fminf(s0, s1);
        float M23 = fmaxf(s2, s3), L23 = fminf(s2, s3);
        int   d01 = (s1 > s0) ? 1 : 0;
        int   d23 = (s3 > s2) ? 3 : 2;
        bool  cp  = (M23 > M01);
        float within2 = fmaxf(fminf(M01, M23), cp ? L23 : L01);
        int   dd  = cp ? d23 : d01;
        ii[g] = cbase + tt[g] * 16 + hi * 4 + dd;
        ss[g] = fmaxf(b2v[g], within2);
    }

#pragma unroll
    for (int off = 16; off <= 32; off <<= 1) {
#pragma unroll
        for (int g = 0; g < 4; ++g) {
            float ob = __shfl_xor(bb[g], off);
            float os = __shfl_xor(ss[g], off);
            int   oi = __shfl_xor(ii[g], off);
            ss[g] = fmaxf(fmaxf(fminf(bb[g], ob), os), ss[g]);
            ii[g] = (ob > bb[g]) ? oi : ii[g];
            bb[g] = fmaxf(bb[g], ob);
        }
    }

    __shared__ float Lb[4][64];
    __shared__ float Ls[4][64];
    __shared__ int   Li[4][64];
    __shared__ int   flags[64];
    if (lane < 16) {
#pragma unroll
        for (int g = 0; g < 4; ++g) {
            Lb[w][g * 16 + lane] = bb[g];
            Ls[w][g * 16 + lane] = ss[g];
            Li[w][g * 16 + lane] = ii[g];
        }
    }
    __syncthreads();

    if (tid < 64) {
        float B = Lb[0][tid], S = Ls[0][tid];
        int   I = Li[0][tid];
#pragma unroll
        for (int w2 = 1; w2 < 4; ++w2) {
            float ob = Lb[w2][tid], os = Ls[w2][tid];
            int   oi = Li[w2][tid];
            S = fmaxf(fmaxf(fminf(B, ob), os), S);
            I = (ob > B) ? oi : I;
            B = fmaxf(B, ob);
        }
        idx[rb + tid] = I;
        flags[tid] = (B - S < REFINE_THR_Q) ? 1 : 0;
    }
    __syncthreads();

    // ---- fused exact f64 rescan for flagged rows (block-uniform, rare)
    __shared__ double sv[256];
    __shared__ int    sx[256];
    for (int r = 0; r < 64; ++r) {
        if (flags[r] == 0) continue;
        int rrow = rb + r;
        const float4* zr4 = (const float4*)(zE + (size_t)rrow * LD);
        float4 zv[16];
#pragma unroll
        for (int q = 0; q < 16; ++q) zv[q] = zr4[q];
        double best = 1.0e300;
        int bi = NEMB;
#pragma unroll 2
        for (int c = 0; c < 8; ++c) {
            int k = tid * 8 + c;
            const float4* er = (const float4*)(emb + (size_t)k * LD);
            double d0 = 0.0, d1 = 0.0, d2 = 0.0, d3 = 0.0;
#pragma unroll
            for (int q = 0; q < 16; ++q) {
                float4 e4 = er[q];
                double tx = (double)zv[q].x - (double)e4.x;
                double ty = (double)zv[q].y - (double)e4.y;
                double tz = (double)zv[q].z - (double)e4.z;
                double tw = (double)zv[q].w - (double)e4.w;
                d0 += tx * tx; d1 += ty * ty; d2 += tz * tz; d3 += tw * tw;
            }
            double d = (d0 + d1) + (d2 + d3);
            if (d < best) { best = d; bi = k; }
        }
        sv[tid] = best; sx[tid] = bi;
        __syncthreads();
        for (int s = 128; s > 0; s >>= 1) {
            if (tid < s) {
                if (sv[tid + s] < sv[tid] ||
                    (sv[tid + s] == sv[tid] && sx[tid + s] < sx[tid])) {
                    sv[tid] = sv[tid + s]; sx[tid] = sx[tid + s];
                }
            }
            __syncthreads();
        }
        if (tid == 0) idx[rrow] = sx[0];
        __syncthreads();
    }
}

// ---------------------------------------------------------------------------
// DEC v3 (MFMA split-bf16, 3 terms) — proven rounds 11-14.
// ---------------------------------------------------------------------------
__global__ __launch_bounds__(256, 2) void k_dec(const int* __restrict__ idx,
                                                const float* __restrict__ emb,
                                                const unsigned short* __restrict__ w1h,
                                                const unsigned short* __restrict__ w1l,
                                                const float* __restrict__ b1,
                                                const unsigned short* __restrict__ w2h,
                                                const unsigned short* __restrict__ w2l,
                                                const float* __restrict__ b2,
                                                float* __restrict__ xrec,
                                                float* __restrict__ zq) {
    __shared__ float hds[4][16 * 68];
    int tid  = threadIdx.x;
    int lane = tid & 63;
    int w    = tid >> 6;
    int lo   = lane & 15;
    int hi   = lane >> 4;
    int rb   = blockIdx.x * 64 + w * 16;
    int row  = rb + lo;
    int ix   = idx[row];

    short8 zah[2], zal[2];
    {
        const float* er  = emb + (size_t)ix * LD + hi * 8;
        float* zqr = zq + (size_t)row * LD + hi * 8;
#pragma unroll
        for (int kt = 0; kt < 2; ++kt) {
            float4 a = *(const float4*)(er + kt * 32);
            float4 b = *(const float4*)(er + kt * 32 + 4);
            *(float4*)(zqr + kt * 32) = a;
            *(float4*)(zqr + kt * 32 + 4) = b;
            float v[8] = {a.x, a.y, a.z, a.w, b.x, b.y, b.z, b.w};
            unsigned short hh[8], ll[8];
#pragma unroll
            for (int q = 0; q < 8; ++q) {
                unsigned short hb = f2bf(v[q]);
                hh[q] = hb;
                ll[q] = f2bf(v[q] - bf2f(hb));
            }
            zah[kt] = *(short8*)hh;
            zal[kt] = *(short8*)ll;
        }
    }

#pragma unroll
    for (int jt = 0; jt < 4; ++jt) {
        float bj = b1[jt * 16 + lo];
        f32x4 c = {bj, bj, bj, bj};
#pragma unroll
        for (int kt = 0; kt < 2; ++kt) {
            short8 bh8 = *(const short8*)(w1h + (jt * 16 + lo) * LD + kt * 32 + hi * 8);
            short8 bl8 = *(const short8*)(w1l + (jt * 16 + lo) * LD + kt * 32 + hi * 8);
            c = __builtin_amdgcn_mfma_f32_16x16x32_bf16(zah[kt], bh8, c, 0, 0, 0);
            c = __builtin_amdgcn_mfma_f32_16x16x32_bf16(zah[kt], bl8, c, 0, 0, 0);
            c = __builtin_amdgcn_mfma_f32_16x16x32_bf16(zal[kt], bh8, c, 0, 0, 0);
        }
#pragma unroll
        for (int r = 0; r < 4; ++r)
            hds[w][(hi * 4 + r) * 68 + jt * 16 + lo] = fmaxf(c[r], 0.f);
    }
    __syncthreads();

    short8 hah[2], hal[2];
#pragma unroll
    for (int kt = 0; kt < 2; ++kt) {
        float4 a = *(const float4*)&hds[w][lo * 68 + kt * 32 + hi * 8];
        float4 b = *(const float4*)&hds[w][lo * 68 + kt * 32 + hi * 8 + 4];
        float v[8] = {a.x, a.y, a.z, a.w, b.x, b.y, b.z, b.w};
        unsigned short hh[8], ll[8];
#pragma unroll
        for (int q = 0; q < 8; ++q) {
            unsigned short hb = f2bf(v[q]);
            hh[q] = hb;
            ll[q] = f2bf(v[q] - bf2f(hb));
        }
        hah[kt] = *(short8*)hh;
        hal[kt] = *(short8*)ll;
    }

    for (int jt = 0; jt < 16; ++jt) {
        float bj = b2[jt * 16 + lo];
        f32x4 c = {bj, bj, bj, bj};
#pragma unroll
        for (int kt = 0; kt < 2; ++kt) {
            short8 bh8 = *(const short8*)(w2h + (jt * 16 + lo) * LD + kt * 32 + hi * 8);
            short8 bl8 = *(const short8*)(w2l + (jt * 16 + lo) * LD + kt * 32 + hi * 8);
            c = __builtin_amdgcn_mfma_f32_16x16x32_bf16(hah[kt], bh8, c, 0, 0, 0);
            c = __builtin_amdgcn_mfma_f32_16x16x32_bf16(hah[kt], bl8, c, 0, 0, 0);
            c = __builtin_amdgcn_mfma_f32_16x16x32_bf16(hal[kt], bh8, c, 0, 0, 0);
        }
#pragma unroll
        for (int r = 0; r < 4; ++r)
            xrec[(size_t)(rb + hi * 4 + r) * SD + jt * 16 + lo] = c[r];
    }
}

// ---------------------------------------------------------------------------
extern "C" void kernel_launch(void* const* d_in, const int* in_sizes, int n_in,
                              void* d_out, int out_size, void* d_ws, size_t ws_size,
                              hipStream_t stream) {
    const float* x   = (const float*)d_in[0];
    const float* ew1 = (const float*)d_in[1];
    const float* eb1 = (const float*)d_in[2];
    const float* ew2 = (const float*)d_in[3];
    const float* eb2 = (const float*)d_in[4];
    const float* emb = (const float*)d_in[5];
    const float* dw1 = (const float*)d_in[6];
    const float* db1 = (const float*)d_in[7];
    const float* dw2 = (const float*)d_in[8];
    const float* db2 = (const float*)d_in[9];

    float* out  = (float*)d_out;
    float* xrec = out;                               // [B,256] (written LAST)
    float* zE   = out + (size_t)BATCH * SD;          // [B,64]
    float* zQ   = zE + (size_t)BATCH * LD;           // [B,64]

    // transient scratch inside the x_recon region (dead once k_dec writes):
    char* xb = (char*)xrec;
    unsigned short* zh   = (unsigned short*)xb;                        // 4 MB
    unsigned short* zl   = (unsigned short*)(xb + (4u << 20));         // 4 MB
    unsigned short* eh   = (unsigned short*)(xb + (8u << 20));         // 256 KB
    unsigned short* el   = (unsigned short*)(xb + (8u << 20) + (NEMB * LD * 2)); // 256 KB
    float*          e2q  = (float*)(xb + (9u << 20));                  // 8 KB
    unsigned short* w1eh = (unsigned short*)(xb + (10u << 20));        // 32 KB
    unsigned short* w1em = w1eh + 16384;                               // 32 KB
    unsigned short* w1el = w1em + 16384;                               // 32 KB
    unsigned short* w2eh = w1el + 16384;                               // 8 KB
    unsigned short* w2em = w2eh + 4096;                                // 8 KB
    unsigned short* w2el = w2em + 4096;                                // 8 KB

    char* ws = (char*)d_ws;
    int*  idxA  = (int*)(ws + 16384);                           // 128 KB
    unsigned short* w1h = (unsigned short*)(ws + 278528);       // 8 KB
    unsigned short* w1l = (unsigned short*)(ws + 286720);       // 8 KB
    unsigned short* w2h = (unsigned short*)(ws + 294912);       // 32 KB
    unsigned short* w2l = (unsigned short*)(ws + 327680);       // 32 KB

    hipLaunchKernelGGL(k0_all,  dim3(168),        dim3(256), 0, stream,
                       emb, dw1, dw2, ew1, ew2, e2q, eh, el,
                       w1h, w1l, w2h, w2l, w1eh, w1em, w1el, w2eh, w2em, w2el);
    hipLaunchKernelGGL(k_enc,   dim3(BATCH / 64), dim3(256), 0, stream,
                       x, w1eh, w1em, w1el, eb1, w2eh, w2em, w2el, eb2, zE, zh, zl);
    hipLaunchKernelGGL(k2_mfma, dim3(BATCH / 64), dim3(256), 0, stream,
                       zh, zl, eh, el, e2q, zE, emb, idxA);
    hipLaunchKernelGGL(k_dec,   dim3(BATCH / 64), dim3(256), 0, stream,
                       idxA, emb, w1h, w1l, db1, w2h, w2l, db2, xrec, zQ);
}

// Round 16
// 127.960 us; speedup vs baseline: 1.0062x; 1.0062x over previous
//
#include <hip/hip_runtime.h>

#define BATCH   32768
#define SD      256
#define LD      64
#define HDIM    64
#define NEMB    2048
#define REFINE_THR_Q 5e-4f   // gap in q-units; s-gap = 2*q-gap -> 1e-3 effective

typedef short  short8 __attribute__((ext_vector_type(8)));
typedef float  f32x4  __attribute__((ext_vector_type(4)));

__device__ __forceinline__ unsigned short f2bf(float f) {
    unsigned int u = __float_as_uint(f);
    u = (u + 0x7FFFu + ((u >> 16) & 1u)) >> 16;
    return (unsigned short)u;
}
__device__ __forceinline__ float bf2f(unsigned short h) {
    return __uint_as_float(((unsigned int)h) << 16);
}

// ---------------------------------------------------------------------------
// K0 (merged): b 0..7   codebook e2q + 2-way split eh/el (+ count=0)
//              b 8..23  dec_w1 2-way split transposed [j][k]
//              b 24..87 dec_w2 2-way split transposed [j][k]
//              b 88..151 enc_w1 3-way split transposed [j(64)][k(256)]
//              b 152..167 enc_w2 3-way split transposed [j(64)][k(64)]
// ---------------------------------------------------------------------------
__global__ __launch_bounds__(256) void k0_all(const float* __restrict__ emb,
                                              const float* __restrict__ dw1,
                                              const float* __restrict__ dw2,
                                              const float* __restrict__ ew1,
                                              const float* __restrict__ ew2,
                                              float* __restrict__ e2q,
                                              unsigned short* __restrict__ eh,
                                              unsigned short* __restrict__ el,
                                              unsigned short* __restrict__ w1h,
                                              unsigned short* __restrict__ w1l,
                                              unsigned short* __restrict__ w2h,
                                              unsigned short* __restrict__ w2l,
                                              unsigned short* __restrict__ w1eh,
                                              unsigned short* __restrict__ w1em,
                                              unsigned short* __restrict__ w1el,
                                              unsigned short* __restrict__ w2eh,
                                              unsigned short* __restrict__ w2em,
                                              unsigned short* __restrict__ w2el,
                                              int* __restrict__ count) {
    int b = blockIdx.x;
    int t = threadIdx.x;
    if (b < 8) {
        int k = b * 256 + t;
        if (k == 0) *count = 0;
        const float* er = emb + (size_t)k * LD;
        unsigned short hrow[LD], lrow[LD];
        float s = 0.f;
#pragma unroll
        for (int q = 0; q < LD; ++q) {
            float v = er[q];
            s += v * v;
            unsigned short h = f2bf(v);
            hrow[q] = h;
            lrow[q] = f2bf(v - bf2f(h));
        }
        e2q[k] = -0.5f * s;
        short8* dh = (short8*)(eh + (size_t)k * LD);
        short8* dl = (short8*)(el + (size_t)k * LD);
#pragma unroll
        for (int q = 0; q < 8; ++q) {
            dh[q] = *(short8*)&hrow[q * 8];
            dl[q] = *(short8*)&lrow[q * 8];
        }
    } else if (b < 24) {
        int e = (b - 8) * 256 + t;
        int j = e >> 6, k = e & 63;
        float v = dw1[k * HDIM + j];
        unsigned short h = f2bf(v);
        w1h[e] = h; w1l[e] = f2bf(v - bf2f(h));
    } else if (b < 88) {
        int e = (b - 24) * 256 + t;
        int j = e >> 6, k = e & 63;
        float v = dw2[k * SD + j];
        unsigned short h = f2bf(v);
        w2h[e] = h; w2l[e] = f2bf(v - bf2f(h));
    } else if (b < 152) {
        int e = (b - 88) * 256 + t;      // [j][k]: j = e>>8, k = e&255
        int j = e >> 8, k = e & 255;
        float v = ew1[k * HDIM + j];
        unsigned short h = f2bf(v);
        float r1 = v - bf2f(h);
        unsigned short m = f2bf(r1);
        float r2 = r1 - bf2f(m);
        w1eh[e] = h; w1em[e] = m; w1el[e] = f2bf(r2);
    } else {
        int e = (b - 152) * 256 + t;     // [j][k]: j = e>>6, k = e&63
        int j = e >> 6, k = e & 63;
        float v = ew2[k * LD + j];
        unsigned short h = f2bf(v);
        float r1 = v - bf2f(h);
        unsigned short m = f2bf(r1);
        float r2 = r1 - bf2f(m);
        w2eh[e] = h; w2em[e] = m; w2el[e] = f2bf(r2);
    }
}

// ---------------------------------------------------------------------------
// ENC v5 (MFMA, 6-term split = f32-equivalent precision) — round-15 proven.
// ---------------------------------------------------------------------------
#define MF(Afr, Bfr, C) __builtin_amdgcn_mfma_f32_16x16x32_bf16(Afr, Bfr, C, 0, 0, 0)

__global__ __launch_bounds__(256, 2) void k_enc(const float* __restrict__ x,
                                                const unsigned short* __restrict__ w1eh,
                                                const unsigned short* __restrict__ w1em,
                                                const unsigned short* __restrict__ w1el,
                                                const float* __restrict__ b1,
                                                const unsigned short* __restrict__ w2eh,
                                                const unsigned short* __restrict__ w2em,
                                                const unsigned short* __restrict__ w2el,
                                                const float* __restrict__ b2,
                                                float* __restrict__ zOut,
                                                unsigned short* __restrict__ zh,
                                                unsigned short* __restrict__ zl) {
    __shared__ float hds[4][16 * 68];
    int tid  = threadIdx.x;
    int lane = tid & 63;
    int w    = tid >> 6;
    int lo   = lane & 15;
    int hi   = lane >> 4;
    int rb   = blockIdx.x * 64 + w * 16;
    int row  = rb + lo;

    // ---- layer 1: c1[jt] = x @ w1 + b1 over K=256
    f32x4 c1[4];
#pragma unroll
    for (int jt = 0; jt < 4; ++jt) {
        float bj = b1[jt * 16 + lo];
        f32x4 c = {bj, bj, bj, bj};
        c1[jt] = c;
    }

#pragma unroll
    for (int kt = 0; kt < 8; ++kt) {
        const float* xp = x + (size_t)row * SD + kt * 32 + hi * 8;
        float4 a4 = *(const float4*)xp;
        float4 b4 = *(const float4*)(xp + 4);
        float v[8] = {a4.x, a4.y, a4.z, a4.w, b4.x, b4.y, b4.z, b4.w};
        unsigned short sh[8], sm[8], sl[8];
#pragma unroll
        for (int q = 0; q < 8; ++q) {
            unsigned short h = f2bf(v[q]);
            float r1 = v[q] - bf2f(h);
            unsigned short m = f2bf(r1);
            float r2 = r1 - bf2f(m);
            sh[q] = h; sm[q] = m; sl[q] = f2bf(r2);
        }
        short8 ah = *(short8*)sh, am = *(short8*)sm, al = *(short8*)sl;
#pragma unroll
        for (int jt = 0; jt < 4; ++jt) {
            size_t wo = (size_t)(jt * 16 + lo) * SD + kt * 32 + hi * 8;
            short8 bh8 = *(const short8*)(w1eh + wo);
            short8 bm8 = *(const short8*)(w1em + wo);
            short8 bl8 = *(const short8*)(w1el + wo);
            f32x4 c = c1[jt];
            c = MF(al, bh8, c);      // small terms first
            c = MF(am, bm8, c);
            c = MF(ah, bl8, c);
            c = MF(am, bh8, c);
            c = MF(ah, bm8, c);
            c = MF(ah, bh8, c);
            c1[jt] = c;
        }
    }
    // relu -> per-wave LDS stripe (C layout: row=hi*4+r, col=jt*16+lo)
#pragma unroll
    for (int jt = 0; jt < 4; ++jt)
#pragma unroll
        for (int r = 0; r < 4; ++r)
            hds[w][(hi * 4 + r) * 68 + jt * 16 + lo] = fmaxf(c1[jt][r], 0.f);
    __syncthreads();

    // ---- layer 2: z = hd @ w2 + b2 over K=64
    f32x4 c2[4];
#pragma unroll
    for (int jt = 0; jt < 4; ++jt) {
        float bj = b2[jt * 16 + lo];
        f32x4 c = {bj, bj, bj, bj};
        c2[jt] = c;
    }
#pragma unroll
    for (int kt = 0; kt < 2; ++kt) {
        float4 a4 = *(const float4*)&hds[w][lo * 68 + kt * 32 + hi * 8];
        float4 b4 = *(const float4*)&hds[w][lo * 68 + kt * 32 + hi * 8 + 4];
        float v[8] = {a4.x, a4.y, a4.z, a4.w, b4.x, b4.y, b4.z, b4.w};
        unsigned short sh[8], sm[8], sl[8];
#pragma unroll
        for (int q = 0; q < 8; ++q) {
            unsigned short h = f2bf(v[q]);
            float r1 = v[q] - bf2f(h);
            unsigned short m = f2bf(r1);
            float r2 = r1 - bf2f(m);
            sh[q] = h; sm[q] = m; sl[q] = f2bf(r2);
        }
        short8 ah = *(short8*)sh, am = *(short8*)sm, al = *(short8*)sl;
#pragma unroll
        for (int jt = 0; jt < 4; ++jt) {
            size_t wo = (size_t)(jt * 16 + lo) * LD + kt * 32 + hi * 8;
            short8 bh8 = *(const short8*)(w2eh + wo);
            short8 bm8 = *(const short8*)(w2em + wo);
            short8 bl8 = *(const short8*)(w2el + wo);
            f32x4 c = c2[jt];
            c = MF(al, bh8, c);
            c = MF(am, bm8, c);
            c = MF(ah, bl8, c);
            c = MF(am, bh8, c);
            c = MF(ah, bm8, c);
            c = MF(ah, bh8, c);
            c2[jt] = c;
        }
    }
#pragma unroll
    for (int jt = 0; jt < 4; ++jt) {
#pragma unroll
        for (int r = 0; r < 4; ++r) {
            float z = c2[jt][r];
            size_t o = (size_t)(rb + hi * 4 + r) * LD + jt * 16 + lo;
            zOut[o] = z;
            unsigned short hb = f2bf(z);
            zh[o] = hb;
            zl[o] = f2bf(z - bf2f(hb));
        }
    }
}

// ---------------------------------------------------------------------------
// K2: MFMA split-bf16 screen (round-14 proven slim form: VGPR 80, occupancy
// 19%, 43.3 us). Flags near-ties to list for the separate k3 pass.
// ---------------------------------------------------------------------------
#define K2_LOAD(P, t) do {                                                  \
    const unsigned short* ph_ = ehp + (size_t)(t) * 16 * LD;                \
    const unsigned short* pl_ = elp + (size_t)(t) * 16 * LD;                \
    P##a0 = *(const short8*)(ph_);                                          \
    P##a1 = *(const short8*)(ph_ + 32);                                     \
    P##a2 = *(const short8*)(pl_);                                          \
    P##a3 = *(const short8*)(pl_ + 32);                                     \
    P##e2 = *(const f32x4*)(e2q + cbase + (t) * 16 + hi * 4);               \
} while (0)

#define K2_COMP(P, t) do {                                                  \
    f32x4 acc_[4];                                                          \
    _Pragma("unroll")                                                       \
    for (int g = 0; g < 4; ++g) {                                           \
        f32x4 c_;                                                           \
        c_ = __builtin_amdgcn_mfma_f32_16x16x32_bf16(P##a0, bh[g][0], P##e2, 0, 0, 0); \
        c_ = __builtin_amdgcn_mfma_f32_16x16x32_bf16(P##a1, bh[g][1], c_, 0, 0, 0);    \
        c_ = __builtin_amdgcn_mfma_f32_16x16x32_bf16(P##a2, bh[g][0], c_, 0, 0, 0);    \
        c_ = __builtin_amdgcn_mfma_f32_16x16x32_bf16(P##a3, bh[g][1], c_, 0, 0, 0);    \
        c_ = __builtin_amdgcn_mfma_f32_16x16x32_bf16(P##a0, bl[g][0], c_, 0, 0, 0);    \
        c_ = __builtin_amdgcn_mfma_f32_16x16x32_bf16(P##a1, bl[g][1], c_, 0, 0, 0);    \
        acc_[g] = c_;                                                       \
    }                                                                       \
    _Pragma("unroll")                                                       \
    for (int g = 0; g < 4; ++g) {                                           \
        float m_ = fmaxf(fmaxf(acc_[g][0], acc_[g][1]),                     \
                         fmaxf(acc_[g][2], acc_[g][3]));                    \
        bool win_ = (m_ > bb[g]);                                           \
        qv[g] = win_ ? acc_[g] : qv[g];                                     \
        tt[g] = win_ ? (t) : tt[g];                                         \
        b2v[g] = fmaxf(b2v[g], fminf(bb[g], m_));                           \
        bb[g] = fmaxf(bb[g], m_);                                           \
    }                                                                       \
} while (0)

__global__ __launch_bounds__(256, 2) void k2_mfma(const unsigned short* __restrict__ zh,
                                                  const unsigned short* __restrict__ zl,
                                                  const unsigned short* __restrict__ eh,
                                                  const unsigned short* __restrict__ el,
                                                  const float* __restrict__ e2q,
                                                  int* __restrict__ idx,
                                                  int* __restrict__ list,
                                                  int* __restrict__ count) {
    int tid  = threadIdx.x;
    int lane = tid & 63;
    int w    = tid >> 6;
    int rb   = blockIdx.x * 64;
    int lo   = lane & 15;
    int hi   = lane >> 4;

    short8 bh[4][2], bl[4][2];
#pragma unroll
    for (int g = 0; g < 4; ++g) {
        size_t zo = (size_t)(rb + g * 16 + lo) * LD + hi * 8;
        bh[g][0] = *(const short8*)(zh + zo);
        bh[g][1] = *(const short8*)(zh + zo + 32);
        bl[g][0] = *(const short8*)(zl + zo);
        bl[g][1] = *(const short8*)(zl + zo + 32);
    }

    float bb[4], b2v[4];
    f32x4 qv[4];
    int   tt[4];
#pragma unroll
    for (int g = 0; g < 4; ++g) {
        bb[g] = -3.0e38f; b2v[g] = -3.0e38f; tt[g] = 0;
        qv[g][0] = qv[g][1] = qv[g][2] = qv[g][3] = -3.0e38f;
    }

    const int cbase = w * (NEMB / 4);
    const unsigned short* ehp = eh + (size_t)(cbase + lo) * LD + hi * 8;
    const unsigned short* elp = el + (size_t)(cbase + lo) * LD + hi * 8;

    short8 Aa0, Aa1, Aa2, Aa3; f32x4 Ae2;
    short8 Ba0, Ba1, Ba2, Ba3; f32x4 Be2;
    short8 Ca0, Ca1, Ca2, Ca3; f32x4 Ce2;

    K2_LOAD(A, 0);
    K2_LOAD(B, 1);
    K2_LOAD(C, 2);

    for (int tb = 0; tb < 27; tb += 3) {
        K2_COMP(A, tb);     K2_LOAD(A, tb + 3);
        K2_COMP(B, tb + 1); K2_LOAD(B, tb + 4);
        K2_COMP(C, tb + 2); K2_LOAD(C, tb + 5);
    }
    K2_COMP(A, 27); K2_LOAD(A, 30);
    K2_COMP(B, 28); K2_LOAD(B, 31);
    K2_COMP(C, 29);
    K2_COMP(A, 30);
    K2_COMP(B, 31);

    float ss[4];
    int   ii[4];
#pragma unroll
    for (int g = 0; g < 4; ++g) {
        float s0 = qv[g][0], s1 = qv[g][1], s2 = qv[g][2], s3 = qv[g][3];
        float M01 = fmaxf(s0, s1), L01 = fminf(s0, s1);
        float M23 = fmaxf(s2, s3), L23 = fminf(s2, s3);
        int   d01 = (s1 > s0) ? 1 : 0;
        int   d23 = (s3 > s2) ? 3 : 2;
        bool  cp  = (M23 > M01);
        float within2 = fmaxf(fminf(M01, M23), cp ? L23 : L01);
        int   dd  = cp ? d23 : d01;
        ii[g] = cbase + tt[g] * 16 + hi * 4 + dd;
        ss[g] = fmaxf(b2v[g], within2);
    }

#pragma unroll
    for (int off = 16; off <= 32; off <<= 1) {
#pragma unroll
        for (int g = 0; g < 4; ++g) {
            float ob = __shfl_xor(bb[g], off);
            float os = __shfl_xor(ss[g], off);
            int   oi = __shfl_xor(ii[g], off);
            ss[g] = fmaxf(fmaxf(fminf(bb[g], ob), os), ss[g]);
            ii[g] = (ob > bb[g]) ? oi : ii[g];
            bb[g] = fmaxf(bb[g], ob);
        }
    }

    __shared__ float Lb[4][64];
    __shared__ float Ls[4][64];
    __shared__ int   Li[4][64];
    if (lane < 16) {
#pragma unroll
        for (int g = 0; g < 4; ++g) {
            Lb[w][g * 16 + lane] = bb[g];
            Ls[w][g * 16 + lane] = ss[g];
            Li[w][g * 16 + lane] = ii[g];
        }
    }
    __syncthreads();

    if (tid < 64) {
        float B = Lb[0][tid], S = Ls[0][tid];
        int   I = Li[0][tid];
#pragma unroll
        for (int w2 = 1; w2 < 4; ++w2) {
            float ob = Lb[w2][tid], os = Ls[w2][tid];
            int   oi = Li[w2][tid];
            S = fmaxf(fmaxf(fminf(B, ob), os), S);
            I = (ob > B) ? oi : I;
            B = fmaxf(B, ob);
        }
        idx[rb + tid] = I;
        if (B - S < REFINE_THR_Q) {
            int p = atomicAdd(count, 1);
            list[p] = rb + tid;
        }
    }
}

// ---------------------------------------------------------------------------
// K3: exact f64 rescan of flagged near-tie rows (separate launch, proven).
// ---------------------------------------------------------------------------
__global__ __launch_bounds__(256) void k3_refine(const float* __restrict__ z,
                                                 const float* __restrict__ emb,
                                                 const int* __restrict__ count,
                                                 const int* __restrict__ list,
                                                 int* __restrict__ idx) {
    __shared__ double sv[256];
    __shared__ int    sx[256];
    int tid = threadIdx.x;
    int n = *count;
    for (int g = blockIdx.x; g < n; g += gridDim.x) {
        int row = list[g];
        const float4* zr4 = (const float4*)(z + (size_t)row * LD);
        float4 zv[16];
#pragma unroll
        for (int q = 0; q < 16; ++q) zv[q] = zr4[q];

        double best = 1.0e300;
        int bi = NEMB;
#pragma unroll 2
        for (int c = 0; c < 8; ++c) {
            int k = tid * 8 + c;
            const float4* er = (const float4*)(emb + (size_t)k * LD);
            double d0 = 0.0, d1 = 0.0, d2 = 0.0, d3 = 0.0;
#pragma unroll
            for (int q = 0; q < 16; ++q) {
                float4 e4 = er[q];
                double tx = (double)zv[q].x - (double)e4.x;
                double ty = (double)zv[q].y - (double)e4.y;
                double tz = (double)zv[q].z - (double)e4.z;
                double tw = (double)zv[q].w - (double)e4.w;
                d0 += tx * tx; d1 += ty * ty; d2 += tz * tz; d3 += tw * tw;
            }
            double d = (d0 + d1) + (d2 + d3);
            if (d < best) { best = d; bi = k; }
        }
        sv[tid] = best; sx[tid] = bi;
        __syncthreads();
        for (int s = 128; s > 0; s >>= 1) {
            if (tid < s) {
                if (sv[tid + s] < sv[tid] ||
                    (sv[tid + s] == sv[tid] && sx[tid + s] < sx[tid])) {
                    sv[tid] = sv[tid + s]; sx[tid] = sx[tid + s];
                }
            }
            __syncthreads();
        }
        if (tid == 0) idx[row] = sx[0];
        __syncthreads();
    }
}

// ---------------------------------------------------------------------------
// DEC v3 (MFMA split-bf16, 3 terms) — proven rounds 11-15.
// ---------------------------------------------------------------------------
__global__ __launch_bounds__(256, 2) void k_dec(const int* __restrict__ idx,
                                                const float* __restrict__ emb,
                                                const unsigned short* __restrict__ w1h,
                                                const unsigned short* __restrict__ w1l,
                                                const float* __restrict__ b1,
                                                const unsigned short* __restrict__ w2h,
                                                const unsigned short* __restrict__ w2l,
                                                const float* __restrict__ b2,
                                                float* __restrict__ xrec,
                                                float* __restrict__ zq) {
    __shared__ float hds[4][16 * 68];
    int tid  = threadIdx.x;
    int lane = tid & 63;
    int w    = tid >> 6;
    int lo   = lane & 15;
    int hi   = lane >> 4;
    int rb   = blockIdx.x * 64 + w * 16;
    int row  = rb + lo;
    int ix   = idx[row];

    short8 zah[2], zal[2];
    {
        const float* er  = emb + (size_t)ix * LD + hi * 8;
        float* zqr = zq + (size_t)row * LD + hi * 8;
#pragma unroll
        for (int kt = 0; kt < 2; ++kt) {
            float4 a = *(const float4*)(er + kt * 32);
            float4 b = *(const float4*)(er + kt * 32 + 4);
            *(float4*)(zqr + kt * 32) = a;
            *(float4*)(zqr + kt * 32 + 4) = b;
            float v[8] = {a.x, a.y, a.z, a.w, b.x, b.y, b.z, b.w};
            unsigned short hh[8], ll[8];
#pragma unroll
            for (int q = 0; q < 8; ++q) {
                unsigned short hb = f2bf(v[q]);
                hh[q] = hb;
                ll[q] = f2bf(v[q] - bf2f(hb));
            }
            zah[kt] = *(short8*)hh;
            zal[kt] = *(short8*)ll;
        }
    }

#pragma unroll
    for (int jt = 0; jt < 4; ++jt) {
        float bj = b1[jt * 16 + lo];
        f32x4 c = {bj, bj, bj, bj};
#pragma unroll
        for (int kt = 0; kt < 2; ++kt) {
            short8 bh8 = *(const short8*)(w1h + (jt * 16 + lo) * LD + kt * 32 + hi * 8);
            short8 bl8 = *(const short8*)(w1l + (jt * 16 + lo) * LD + kt * 32 + hi * 8);
            c = __builtin_amdgcn_mfma_f32_16x16x32_bf16(zah[kt], bh8, c, 0, 0, 0);
            c = __builtin_amdgcn_mfma_f32_16x16x32_bf16(zah[kt], bl8, c, 0, 0, 0);
            c = __builtin_amdgcn_mfma_f32_16x16x32_bf16(zal[kt], bh8, c, 0, 0, 0);
        }
#pragma unroll
        for (int r = 0; r < 4; ++r)
            hds[w][(hi * 4 + r) * 68 + jt * 16 + lo] = fmaxf(c[r], 0.f);
    }
    __syncthreads();

    short8 hah[2], hal[2];
#pragma unroll
    for (int kt = 0; kt < 2; ++kt) {
        float4 a = *(const float4*)&hds[w][lo * 68 + kt * 32 + hi * 8];
        float4 b = *(const float4*)&hds[w][lo * 68 + kt * 32 + hi * 8 + 4];
        float v[8] = {a.x, a.y, a.z, a.w, b.x, b.y, b.z, b.w};
        unsigned short hh[8], ll[8];
#pragma unroll
        for (int q = 0; q < 8; ++q) {
            unsigned short hb = f2bf(v[q]);
            hh[q] = hb;
            ll[q] = f2bf(v[q] - bf2f(hb));
        }
        hah[kt] = *(short8*)hh;
        hal[kt] = *(short8*)ll;
    }

    for (int jt = 0; jt < 16; ++jt) {
        float bj = b2[jt * 16 + lo];
        f32x4 c = {bj, bj, bj, bj};
#pragma unroll
        for (int kt = 0; kt < 2; ++kt) {
            short8 bh8 = *(const short8*)(w2h + (jt * 16 + lo) * LD + kt * 32 + hi * 8);
            short8 bl8 = *(const short8*)(w2l + (jt * 16 + lo) * LD + kt * 32 + hi * 8);
            c = __builtin_amdgcn_mfma_f32_16x16x32_bf16(hah[kt], bh8, c, 0, 0, 0);
            c = __builtin_amdgcn_mfma_f32_16x16x32_bf16(hah[kt], bl8, c, 0, 0, 0);
            c = __builtin_amdgcn_mfma_f32_16x16x32_bf16(hal[kt], bh8, c, 0, 0, 0);
        }
#pragma unroll
        for (int r = 0; r < 4; ++r)
            xrec[(size_t)(rb + hi * 4 + r) * SD + jt * 16 + lo] = c[r];
    }
}

// ---------------------------------------------------------------------------
extern "C" void kernel_launch(void* const* d_in, const int* in_sizes, int n_in,
                              void* d_out, int out_size, void* d_ws, size_t ws_size,
                              hipStream_t stream) {
    const float* x   = (const float*)d_in[0];
    const float* ew1 = (const float*)d_in[1];
    const float* eb1 = (const float*)d_in[2];
    const float* ew2 = (const float*)d_in[3];
    const float* eb2 = (const float*)d_in[4];
    const float* emb = (const float*)d_in[5];
    const float* dw1 = (const float*)d_in[6];
    const float* db1 = (const float*)d_in[7];
    const float* dw2 = (const float*)d_in[8];
    const float* db2 = (const float*)d_in[9];

    float* out  = (float*)d_out;
    float* xrec = out;                               // [B,256] (written LAST)
    float* zE   = out + (size_t)BATCH * SD;          // [B,64]
    float* zQ   = zE + (size_t)BATCH * LD;           // [B,64]

    // transient scratch inside the x_recon region (dead once k_dec writes):
    char* xb = (char*)xrec;
    unsigned short* zh   = (unsigned short*)xb;                        // 4 MB
    unsigned short* zl   = (unsigned short*)(xb + (4u << 20));         // 4 MB
    unsigned short* eh   = (unsigned short*)(xb + (8u << 20));         // 256 KB
    unsigned short* el   = (unsigned short*)(xb + (8u << 20) + (NEMB * LD * 2)); // 256 KB
    float*          e2q  = (float*)(xb + (9u << 20));                  // 8 KB
    unsigned short* w1eh = (unsigned short*)(xb + (10u << 20));        // 32 KB
    unsigned short* w1em = w1eh + 16384;                               // 32 KB
    unsigned short* w1el = w1em + 16384;                               // 32 KB
    unsigned short* w2eh = w1el + 16384;                               // 8 KB
    unsigned short* w2em = w2eh + 4096;                                // 8 KB
    unsigned short* w2el = w2em + 4096;                                // 8 KB

    char* ws = (char*)d_ws;
    int*  count = (int*)ws;                                     // 4 B
    int*  idxA  = (int*)(ws + 16384);                           // 128 KB
    int*  list  = (int*)(ws + 147456);                          // 128 KB
    unsigned short* w1h = (unsigned short*)(ws + 278528);       // 8 KB
    unsigned short* w1l = (unsigned short*)(ws + 286720);       // 8 KB
    unsigned short* w2h = (unsigned short*)(ws + 294912);       // 32 KB
    unsigned short* w2l = (unsigned short*)(ws + 327680);       // 32 KB

    hipLaunchKernelGGL(k0_all,    dim3(168),        dim3(256), 0, stream,
                       emb, dw1, dw2, ew1, ew2, e2q, eh, el,
                       w1h, w1l, w2h, w2l, w1eh, w1em, w1el, w2eh, w2em, w2el, count);
    hipLaunchKernelGGL(k_enc,     dim3(BATCH / 64), dim3(256), 0, stream,
                       x, w1eh, w1em, w1el, eb1, w2eh, w2em, w2el, eb2, zE, zh, zl);
    hipLaunchKernelGGL(k2_mfma,   dim3(BATCH / 64), dim3(256), 0, stream,
                       zh, zl, eh, el, e2q, idxA, list, count);
    hipLaunchKernelGGL(k3_refine, dim3(128),        dim3(256), 0, stream,
                       zE, emb, count, list, idxA);
    hipLaunchKernelGGL(k_dec,     dim3(BATCH / 64), dim3(256), 0, stream,
                       idxA, emb, w1h, w1l, db1, w2h, w2l, db2, xrec, zQ);
}

// Round 17
// 127.857 us; speedup vs baseline: 1.0070x; 1.0008x over previous
//
#include <hip/hip_runtime.h>

#define BATCH   32768
#define SD      256
#define LD      64
#define HDIM    64
#define NEMB    2048
#define REFINE_THR_Q 5e-4f   // gap in q-units; s-gap = 2*q-gap -> 1e-3 effective

typedef short  short8 __attribute__((ext_vector_type(8)));
typedef float  f32x4  __attribute__((ext_vector_type(4)));

__device__ __forceinline__ unsigned short f2bf(float f) {
    unsigned int u = __float_as_uint(f);
    u = (u + 0x7FFFu + ((u >> 16) & 1u)) >> 16;
    return (unsigned short)u;
}
__device__ __forceinline__ float bf2f(unsigned short h) {
    return __uint_as_float(((unsigned int)h) << 16);
}

// ---------------------------------------------------------------------------
// K0 (merged): b 0..7   codebook e2q + 2-way split eh/el (+ count=0)
//              b 8..23  dec_w1 2-way split transposed [j][k]
//              b 24..87 dec_w2 2-way split transposed [j][k]
//              b 88..151 enc_w1 3-way split transposed [j(64)][k(256)]
//              b 152..167 enc_w2 3-way split transposed [j(64)][k(64)]
// ---------------------------------------------------------------------------
__global__ __launch_bounds__(256) void k0_all(const float* __restrict__ emb,
                                              const float* __restrict__ dw1,
                                              const float* __restrict__ dw2,
                                              const float* __restrict__ ew1,
                                              const float* __restrict__ ew2,
                                              float* __restrict__ e2q,
                                              unsigned short* __restrict__ eh,
                                              unsigned short* __restrict__ el,
                                              unsigned short* __restrict__ w1h,
                                              unsigned short* __restrict__ w1l,
                                              unsigned short* __restrict__ w2h,
                                              unsigned short* __restrict__ w2l,
                                              unsigned short* __restrict__ w1eh,
                                              unsigned short* __restrict__ w1em,
                                              unsigned short* __restrict__ w1el,
                                              unsigned short* __restrict__ w2eh,
                                              unsigned short* __restrict__ w2em,
                                              unsigned short* __restrict__ w2el,
                                              int* __restrict__ count) {
    int b = blockIdx.x;
    int t = threadIdx.x;
    if (b < 8) {
        int k = b * 256 + t;
        if (k == 0) *count = 0;
        const float* er = emb + (size_t)k * LD;
        unsigned short hrow[LD], lrow[LD];
        float s = 0.f;
#pragma unroll
        for (int q = 0; q < LD; ++q) {
            float v = er[q];
            s += v * v;
            unsigned short h = f2bf(v);
            hrow[q] = h;
            lrow[q] = f2bf(v - bf2f(h));
        }
        e2q[k] = -0.5f * s;
        short8* dh = (short8*)(eh + (size_t)k * LD);
        short8* dl = (short8*)(el + (size_t)k * LD);
#pragma unroll
        for (int q = 0; q < 8; ++q) {
            dh[q] = *(short8*)&hrow[q * 8];
            dl[q] = *(short8*)&lrow[q * 8];
        }
    } else if (b < 24) {
        int e = (b - 8) * 256 + t;
        int j = e >> 6, k = e & 63;
        float v = dw1[k * HDIM + j];
        unsigned short h = f2bf(v);
        w1h[e] = h; w1l[e] = f2bf(v - bf2f(h));
    } else if (b < 88) {
        int e = (b - 24) * 256 + t;
        int j = e >> 6, k = e & 63;
        float v = dw2[k * SD + j];
        unsigned short h = f2bf(v);
        w2h[e] = h; w2l[e] = f2bf(v - bf2f(h));
    } else if (b < 152) {
        int e = (b - 88) * 256 + t;      // [j][k]: j = e>>8, k = e&255
        int j = e >> 8, k = e & 255;
        float v = ew1[k * HDIM + j];
        unsigned short h = f2bf(v);
        float r1 = v - bf2f(h);
        unsigned short m = f2bf(r1);
        float r2 = r1 - bf2f(m);
        w1eh[e] = h; w1em[e] = m; w1el[e] = f2bf(r2);
    } else {
        int e = (b - 152) * 256 + t;     // [j][k]: j = e>>6, k = e&63
        int j = e >> 6, k = e & 63;
        float v = ew2[k * LD + j];
        unsigned short h = f2bf(v);
        float r1 = v - bf2f(h);
        unsigned short m = f2bf(r1);
        float r2 = r1 - bf2f(m);
        w2eh[e] = h; w2em[e] = m; w2el[e] = f2bf(r2);
    }
}

// ---------------------------------------------------------------------------
// ENC v6 (MFMA 6-term split, K2-style 4-deep named prefetch).
// Same math as round-15 (bit-compatible); restructured so the compiler holds
// 4 weight-triplet buffers + 2 x-pairs live -> loads issued ~4 iters ahead.
// ---------------------------------------------------------------------------
#define MF(Afr, Bfr, C) __builtin_amdgcn_mfma_f32_16x16x32_bf16(Afr, Bfr, C, 0, 0, 0)

#define E_WLOAD(P, I) do {                                                  \
    int kt_ = (I) >> 2, jt_ = (I) & 3;                                      \
    size_t wo_ = (size_t)(jt_ * 16 + lo) * SD + kt_ * 32 + hi * 8;          \
    P##h = *(const short8*)(w1eh + wo_);                                    \
    P##m = *(const short8*)(w1em + wo_);                                    \
    P##l = *(const short8*)(w1el + wo_);                                    \
} while (0)

#define E_COMP(P, JT) do {                                                  \
    f32x4 c_ = c1[JT];                                                      \
    c_ = MF(xl8, P##h, c_);                                                 \
    c_ = MF(xm8, P##m, c_);                                                 \
    c_ = MF(xh8, P##l, c_);                                                 \
    c_ = MF(xm8, P##h, c_);                                                 \
    c_ = MF(xh8, P##m, c_);                                                 \
    c_ = MF(xh8, P##h, c_);                                                 \
    c1[JT] = c_;                                                            \
} while (0)

__global__ __launch_bounds__(256, 2) void k_enc(const float* __restrict__ x,
                                                const unsigned short* __restrict__ w1eh,
                                                const unsigned short* __restrict__ w1em,
                                                const unsigned short* __restrict__ w1el,
                                                const float* __restrict__ b1,
                                                const unsigned short* __restrict__ w2eh,
                                                const unsigned short* __restrict__ w2em,
                                                const unsigned short* __restrict__ w2el,
                                                const float* __restrict__ b2,
                                                float* __restrict__ zOut,
                                                unsigned short* __restrict__ zh,
                                                unsigned short* __restrict__ zl) {
    __shared__ float hds[4][16 * 68];
    int tid  = threadIdx.x;
    int lane = tid & 63;
    int w    = tid >> 6;
    int lo   = lane & 15;
    int hi   = lane >> 4;
    int rb   = blockIdx.x * 64 + w * 16;
    int row  = rb + lo;
    const float* xrow = x + (size_t)row * SD;

    // ---- layer 1: c1[jt] = x @ w1 + b1 over K=256
    f32x4 c1[4];
#pragma unroll
    for (int jt = 0; jt < 4; ++jt) {
        float bj = b1[jt * 16 + lo];
        f32x4 c = {bj, bj, bj, bj};
        c1[jt] = c;
    }

    short8 Ph, Pm, Pl, Qh, Qm, Ql, Rh, Rm, Rl, Sh, Sm, Sl;
    float4 xe0, xe1, xo0, xo1;
    xe0 = *(const float4*)(xrow + 0 * 32 + hi * 8);
    xe1 = *(const float4*)(xrow + 0 * 32 + hi * 8 + 4);
    xo0 = *(const float4*)(xrow + 1 * 32 + hi * 8);
    xo1 = *(const float4*)(xrow + 1 * 32 + hi * 8 + 4);
    E_WLOAD(P, 0); E_WLOAD(Q, 1); E_WLOAD(R, 2); E_WLOAD(S, 3);

#pragma unroll
    for (int kt = 0; kt < 8; ++kt) {
        float4 a4 = (kt & 1) ? xo0 : xe0;
        float4 b4 = (kt & 1) ? xo1 : xe1;
        if (kt + 2 < 8) {                  // prefetch x pair for kt+2 (same parity)
            if (kt & 1) {
                xo0 = *(const float4*)(xrow + (kt + 2) * 32 + hi * 8);
                xo1 = *(const float4*)(xrow + (kt + 2) * 32 + hi * 8 + 4);
            } else {
                xe0 = *(const float4*)(xrow + (kt + 2) * 32 + hi * 8);
                xe1 = *(const float4*)(xrow + (kt + 2) * 32 + hi * 8 + 4);
            }
        }
        // 3-way split of current x fragment
        float v[8] = {a4.x, a4.y, a4.z, a4.w, b4.x, b4.y, b4.z, b4.w};
        unsigned short sh[8], sm[8], sl[8];
#pragma unroll
        for (int q = 0; q < 8; ++q) {
            unsigned short h = f2bf(v[q]);
            float r1 = v[q] - bf2f(h);
            unsigned short m = f2bf(r1);
            float r2 = r1 - bf2f(m);
            sh[q] = h; sm[q] = m; sl[q] = f2bf(r2);
        }
        short8 xh8 = *(short8*)sh, xm8 = *(short8*)sm, xl8 = *(short8*)sl;

        E_COMP(P, 0); if (kt < 7) E_WLOAD(P, kt * 4 + 4);
        E_COMP(Q, 1); if (kt < 7) E_WLOAD(Q, kt * 4 + 5);
        E_COMP(R, 2); if (kt < 7) E_WLOAD(R, kt * 4 + 6);
        E_COMP(S, 3); if (kt < 7) E_WLOAD(S, kt * 4 + 7);
    }

    // relu -> per-wave LDS stripe (C layout: row=hi*4+r, col=jt*16+lo)
#pragma unroll
    for (int jt = 0; jt < 4; ++jt)
#pragma unroll
        for (int r = 0; r < 4; ++r)
            hds[w][(hi * 4 + r) * 68 + jt * 16 + lo] = fmaxf(c1[jt][r], 0.f);
    __syncthreads();

    // ---- layer 2: z = hd @ w2 + b2 over K=64 (weights hot in L2)
    f32x4 c2[4];
#pragma unroll
    for (int jt = 0; jt < 4; ++jt) {
        float bj = b2[jt * 16 + lo];
        f32x4 c = {bj, bj, bj, bj};
        c2[jt] = c;
    }
#pragma unroll
    for (int kt = 0; kt < 2; ++kt) {
        float4 a4 = *(const float4*)&hds[w][lo * 68 + kt * 32 + hi * 8];
        float4 b4 = *(const float4*)&hds[w][lo * 68 + kt * 32 + hi * 8 + 4];
        float v[8] = {a4.x, a4.y, a4.z, a4.w, b4.x, b4.y, b4.z, b4.w};
        unsigned short sh[8], sm[8], sl[8];
#pragma unroll
        for (int q = 0; q < 8; ++q) {
            unsigned short h = f2bf(v[q]);
            float r1 = v[q] - bf2f(h);
            unsigned short m = f2bf(r1);
            float r2 = r1 - bf2f(m);
            sh[q] = h; sm[q] = m; sl[q] = f2bf(r2);
        }
        short8 ah = *(short8*)sh, am = *(short8*)sm, al = *(short8*)sl;
#pragma unroll
        for (int jt = 0; jt < 4; ++jt) {
            size_t wo = (size_t)(jt * 16 + lo) * LD + kt * 32 + hi * 8;
            short8 bh8 = *(const short8*)(w2eh + wo);
            short8 bm8 = *(const short8*)(w2em + wo);
            short8 bl8 = *(const short8*)(w2el + wo);
            f32x4 c = c2[jt];
            c = MF(al, bh8, c);
            c = MF(am, bm8, c);
            c = MF(ah, bl8, c);
            c = MF(am, bh8, c);
            c = MF(ah, bm8, c);
            c = MF(ah, bh8, c);
            c2[jt] = c;
        }
    }
#pragma unroll
    for (int jt = 0; jt < 4; ++jt) {
#pragma unroll
        for (int r = 0; r < 4; ++r) {
            float z = c2[jt][r];
            size_t o = (size_t)(rb + hi * 4 + r) * LD + jt * 16 + lo;
            zOut[o] = z;
            unsigned short hb = f2bf(z);
            zh[o] = hb;
            zl[o] = f2bf(z - bf2f(hb));
        }
    }
}

// ---------------------------------------------------------------------------
// K2: MFMA split-bf16 screen (round-14 proven slim form).
// ---------------------------------------------------------------------------
#define K2_LOAD(P, t) do {                                                  \
    const unsigned short* ph_ = ehp + (size_t)(t) * 16 * LD;                \
    const unsigned short* pl_ = elp + (size_t)(t) * 16 * LD;                \
    P##a0 = *(const short8*)(ph_);                                          \
    P##a1 = *(const short8*)(ph_ + 32);                                     \
    P##a2 = *(const short8*)(pl_);                                          \
    P##a3 = *(const short8*)(pl_ + 32);                                     \
    P##e2 = *(const f32x4*)(e2q + cbase + (t) * 16 + hi * 4);               \
} while (0)

#define K2_COMP(P, t) do {                                                  \
    f32x4 acc_[4];                                                          \
    _Pragma("unroll")                                                       \
    for (int g = 0; g < 4; ++g) {                                           \
        f32x4 c_;                                                           \
        c_ = __builtin_amdgcn_mfma_f32_16x16x32_bf16(P##a0, bh[g][0], P##e2, 0, 0, 0); \
        c_ = __builtin_amdgcn_mfma_f32_16x16x32_bf16(P##a1, bh[g][1], c_, 0, 0, 0);    \
        c_ = __builtin_amdgcn_mfma_f32_16x16x32_bf16(P##a2, bh[g][0], c_, 0, 0, 0);    \
        c_ = __builtin_amdgcn_mfma_f32_16x16x32_bf16(P##a3, bh[g][1], c_, 0, 0, 0);    \
        c_ = __builtin_amdgcn_mfma_f32_16x16x32_bf16(P##a0, bl[g][0], c_, 0, 0, 0);    \
        c_ = __builtin_amdgcn_mfma_f32_16x16x32_bf16(P##a1, bl[g][1], c_, 0, 0, 0);    \
        acc_[g] = c_;                                                       \
    }                                                                       \
    _Pragma("unroll")                                                       \
    for (int g = 0; g < 4; ++g) {                                           \
        float m_ = fmaxf(fmaxf(acc_[g][0], acc_[g][1]),                     \
                         fmaxf(acc_[g][2], acc_[g][3]));                    \
        bool win_ = (m_ > bb[g]);                                           \
        qv[g] = win_ ? acc_[g] : qv[g];                                     \
        tt[g] = win_ ? (t) : tt[g];                                         \
        b2v[g] = fmaxf(b2v[g], fminf(bb[g], m_));                           \
        bb[g] = fmaxf(bb[g], m_);                                           \
    }                                                                       \
} while (0)

__global__ __launch_bounds__(256, 2) void k2_mfma(const unsigned short* __restrict__ zh,
                                                  const unsigned short* __restrict__ zl,
                                                  const unsigned short* __restrict__ eh,
                                                  const unsigned short* __restrict__ el,
                                                  const float* __restrict__ e2q,
                                                  int* __restrict__ idx,
                                                  int* __restrict__ list,
                                                  int* __restrict__ count) {
    int tid  = threadIdx.x;
    int lane = tid & 63;
    int w    = tid >> 6;
    int rb   = blockIdx.x * 64;
    int lo   = lane & 15;
    int hi   = lane >> 4;

    short8 bh[4][2], bl[4][2];
#pragma unroll
    for (int g = 0; g < 4; ++g) {
        size_t zo = (size_t)(rb + g * 16 + lo) * LD + hi * 8;
        bh[g][0] = *(const short8*)(zh + zo);
        bh[g][1] = *(const short8*)(zh + zo + 32);
        bl[g][0] = *(const short8*)(zl + zo);
        bl[g][1] = *(const short8*)(zl + zo + 32);
    }

    float bb[4], b2v[4];
    f32x4 qv[4];
    int   tt[4];
#pragma unroll
    for (int g = 0; g < 4; ++g) {
        bb[g] = -3.0e38f; b2v[g] = -3.0e38f; tt[g] = 0;
        qv[g][0] = qv[g][1] = qv[g][2] = qv[g][3] = -3.0e38f;
    }

    const int cbase = w * (NEMB / 4);
    const unsigned short* ehp = eh + (size_t)(cbase + lo) * LD + hi * 8;
    const unsigned short* elp = el + (size_t)(cbase + lo) * LD + hi * 8;

    short8 Aa0, Aa1, Aa2, Aa3; f32x4 Ae2;
    short8 Ba0, Ba1, Ba2, Ba3; f32x4 Be2;
    short8 Ca0, Ca1, Ca2, Ca3; f32x4 Ce2;

    K2_LOAD(A, 0);
    K2_LOAD(B, 1);
    K2_LOAD(C, 2);

    for (int tb = 0; tb < 27; tb += 3) {
        K2_COMP(A, tb);     K2_LOAD(A, tb + 3);
        K2_COMP(B, tb + 1); K2_LOAD(B, tb + 4);
        K2_COMP(C, tb + 2); K2_LOAD(C, tb + 5);
    }
    K2_COMP(A, 27); K2_LOAD(A, 30);
    K2_COMP(B, 28); K2_LOAD(B, 31);
    K2_COMP(C, 29);
    K2_COMP(A, 30);
    K2_COMP(B, 31);

    float ss[4];
    int   ii[4];
#pragma unroll
    for (int g = 0; g < 4; ++g) {
        float s0 = qv[g][0], s1 = qv[g][1], s2 = qv[g][2], s3 = qv[g][3];
        float M01 = fmaxf(s0, s1), L01 = fminf(s0, s1);
        float M23 = fmaxf(s2, s3), L23 = fminf(s2, s3);
        int   d01 = (s1 > s0) ? 1 : 0;
        int   d23 = (s3 > s2) ? 3 : 2;
        bool  cp  = (M23 > M01);
        float within2 = fmaxf(fminf(M01, M23), cp ? L23 : L01);
        int   dd  = cp ? d23 : d01;
        ii[g] = cbase + tt[g] * 16 + hi * 4 + dd;
        ss[g] = fmaxf(b2v[g], within2);
    }

#pragma unroll
    for (int off = 16; off <= 32; off <<= 1) {
#pragma unroll
        for (int g = 0; g < 4; ++g) {
            float ob = __shfl_xor(bb[g], off);
            float os = __shfl_xor(ss[g], off);
            int   oi = __shfl_xor(ii[g], off);
            ss[g] = fmaxf(fmaxf(fminf(bb[g], ob), os), ss[g]);
            ii[g] = (ob > bb[g]) ? oi : ii[g];
            bb[g] = fmaxf(bb[g], ob);
        }
    }

    __shared__ float Lb[4][64];
    __shared__ float Ls[4][64];
    __shared__ int   Li[4][64];
    if (lane < 16) {
#pragma unroll
        for (int g = 0; g < 4; ++g) {
            Lb[w][g * 16 + lane] = bb[g];
            Ls[w][g * 16 + lane] = ss[g];
            Li[w][g * 16 + lane] = ii[g];
        }
    }
    __syncthreads();

    if (tid < 64) {
        float B = Lb[0][tid], S = Ls[0][tid];
        int   I = Li[0][tid];
#pragma unroll
        for (int w2 = 1; w2 < 4; ++w2) {
            float ob = Lb[w2][tid], os = Ls[w2][tid];
            int   oi = Li[w2][tid];
            S = fmaxf(fmaxf(fminf(B, ob), os), S);
            I = (ob > B) ? oi : I;
            B = fmaxf(B, ob);
        }
        idx[rb + tid] = I;
        if (B - S < REFINE_THR_Q) {
            int p = atomicAdd(count, 1);
            list[p] = rb + tid;
        }
    }
}

// ---------------------------------------------------------------------------
// K3: exact f64 rescan of flagged near-tie rows (separate launch, proven).
// ---------------------------------------------------------------------------
__global__ __launch_bounds__(256) void k3_refine(const float* __restrict__ z,
                                                 const float* __restrict__ emb,
                                                 const int* __restrict__ count,
                                                 const int* __restrict__ list,
                                                 int* __restrict__ idx) {
    __shared__ double sv[256];
    __shared__ int    sx[256];
    int tid = threadIdx.x;
    int n = *count;
    for (int g = blockIdx.x; g < n; g += gridDim.x) {
        int row = list[g];
        const float4* zr4 = (const float4*)(z + (size_t)row * LD);
        float4 zv[16];
#pragma unroll
        for (int q = 0; q < 16; ++q) zv[q] = zr4[q];

        double best = 1.0e300;
        int bi = NEMB;
#pragma unroll 2
        for (int c = 0; c < 8; ++c) {
            int k = tid * 8 + c;
            const float4* er = (const float4*)(emb + (size_t)k * LD);
            double d0 = 0.0, d1 = 0.0, d2 = 0.0, d3 = 0.0;
#pragma unroll
            for (int q = 0; q < 16; ++q) {
                float4 e4 = er[q];
                double tx = (double)zv[q].x - (double)e4.x;
                double ty = (double)zv[q].y - (double)e4.y;
                double tz = (double)zv[q].z - (double)e4.z;
                double tw = (double)zv[q].w - (double)e4.w;
                d0 += tx * tx; d1 += ty * ty; d2 += tz * tz; d3 += tw * tw;
            }
            double d = (d0 + d1) + (d2 + d3);
            if (d < best) { best = d; bi = k; }
        }
        sv[tid] = best; sx[tid] = bi;
        __syncthreads();
        for (int s = 128; s > 0; s >>= 1) {
            if (tid < s) {
                if (sv[tid + s] < sv[tid] ||
                    (sv[tid + s] == sv[tid] && sx[tid + s] < sx[tid])) {
                    sv[tid] = sv[tid + s]; sx[tid] = sx[tid + s];
                }
            }
            __syncthreads();
        }
        if (tid == 0) idx[row] = sx[0];
        __syncthreads();
    }
}

// ---------------------------------------------------------------------------
// DEC v3 (MFMA split-bf16, 3 terms) — proven rounds 11-16.
// ---------------------------------------------------------------------------
__global__ __launch_bounds__(256, 2) void k_dec(const int* __restrict__ idx,
                                                const float* __restrict__ emb,
                                                const unsigned short* __restrict__ w1h,
                                                const unsigned short* __restrict__ w1l,
                                                const float* __restrict__ b1,
                                                const unsigned short* __restrict__ w2h,
                                                const unsigned short* __restrict__ w2l,
                                                const float* __restrict__ b2,
                                                float* __restrict__ xrec,
                                                float* __restrict__ zq) {
    __shared__ float hds[4][16 * 68];
    int tid  = threadIdx.x;
    int lane = tid & 63;
    int w    = tid >> 6;
    int lo   = lane & 15;
    int hi   = lane >> 4;
    int rb   = blockIdx.x * 64 + w * 16;
    int row  = rb + lo;
    int ix   = idx[row];

    short8 zah[2], zal[2];
    {
        const float* er  = emb + (size_t)ix * LD + hi * 8;
        float* zqr = zq + (size_t)row * LD + hi * 8;
#pragma unroll
        for (int kt = 0; kt < 2; ++kt) {
            float4 a = *(const float4*)(er + kt * 32);
            float4 b = *(const float4*)(er + kt * 32 + 4);
            *(float4*)(zqr + kt * 32) = a;
            *(float4*)(zqr + kt * 32 + 4) = b;
            float v[8] = {a.x, a.y, a.z, a.w, b.x, b.y, b.z, b.w};
            unsigned short hh[8], ll[8];
#pragma unroll
            for (int q = 0; q < 8; ++q) {
                unsigned short hb = f2bf(v[q]);
                hh[q] = hb;
                ll[q] = f2bf(v[q] - bf2f(hb));
            }
            zah[kt] = *(short8*)hh;
            zal[kt] = *(short8*)ll;
        }
    }

#pragma unroll
    for (int jt = 0; jt < 4; ++jt) {
        float bj = b1[jt * 16 + lo];
        f32x4 c = {bj, bj, bj, bj};
#pragma unroll
        for (int kt = 0; kt < 2; ++kt) {
            short8 bh8 = *(const short8*)(w1h + (jt * 16 + lo) * LD + kt * 32 + hi * 8);
            short8 bl8 = *(const short8*)(w1l + (jt * 16 + lo) * LD + kt * 32 + hi * 8);
            c = __builtin_amdgcn_mfma_f32_16x16x32_bf16(zah[kt], bh8, c, 0, 0, 0);
            c = __builtin_amdgcn_mfma_f32_16x16x32_bf16(zah[kt], bl8, c, 0, 0, 0);
            c = __builtin_amdgcn_mfma_f32_16x16x32_bf16(zal[kt], bh8, c, 0, 0, 0);
        }
#pragma unroll
        for (int r = 0; r < 4; ++r)
            hds[w][(hi * 4 + r) * 68 + jt * 16 + lo] = fmaxf(c[r], 0.f);
    }
    __syncthreads();

    short8 hah[2], hal[2];
#pragma unroll
    for (int kt = 0; kt < 2; ++kt) {
        float4 a = *(const float4*)&hds[w][lo * 68 + kt * 32 + hi * 8];
        float4 b = *(const float4*)&hds[w][lo * 68 + kt * 32 + hi * 8 + 4];
        float v[8] = {a.x, a.y, a.z, a.w, b.x, b.y, b.z, b.w};
        unsigned short hh[8], ll[8];
#pragma unroll
        for (int q = 0; q < 8; ++q) {
            unsigned short hb = f2bf(v[q]);
            hh[q] = hb;
            ll[q] = f2bf(v[q] - bf2f(hb));
        }
        hah[kt] = *(short8*)hh;
        hal[kt] = *(short8*)ll;
    }

    for (int jt = 0; jt < 16; ++jt) {
        float bj = b2[jt * 16 + lo];
        f32x4 c = {bj, bj, bj, bj};
#pragma unroll
        for (int kt = 0; kt < 2; ++kt) {
            short8 bh8 = *(const short8*)(w2h + (jt * 16 + lo) * LD + kt * 32 + hi * 8);
            short8 bl8 = *(const short8*)(w2l + (jt * 16 + lo) * LD + kt * 32 + hi * 8);
            c = __builtin_amdgcn_mfma_f32_16x16x32_bf16(hah[kt], bh8, c, 0, 0, 0);
            c = __builtin_amdgcn_mfma_f32_16x16x32_bf16(hah[kt], bl8, c, 0, 0, 0);
            c = __builtin_amdgcn_mfma_f32_16x16x32_bf16(hal[kt], bh8, c, 0, 0, 0);
        }
#pragma unroll
        for (int r = 0; r < 4; ++r)
            xrec[(size_t)(rb + hi * 4 + r) * SD + jt * 16 + lo] = c[r];
    }
}

// ---------------------------------------------------------------------------
extern "C" void kernel_launch(void* const* d_in, const int* in_sizes, int n_in,
                              void* d_out, int out_size, void* d_ws, size_t ws_size,
                              hipStream_t stream) {
    const float* x   = (const float*)d_in[0];
    const float* ew1 = (const float*)d_in[1];
    const float* eb1 = (const float*)d_in[2];
    const float* ew2 = (const float*)d_in[3];
    const float* eb2 = (const float*)d_in[4];
    const float* emb = (const float*)d_in[5];
    const float* dw1 = (const float*)d_in[6];
    const float* db1 = (const float*)d_in[7];
    const float* dw2 = (const float*)d_in[8];
    const float* db2 = (const float*)d_in[9];

    float* out  = (float*)d_out;
    float* xrec = out;                               // [B,256] (written LAST)
    float* zE   = out + (size_t)BATCH * SD;          // [B,64]
    float* zQ   = zE + (size_t)BATCH * LD;           // [B,64]

    // transient scratch inside the x_recon region (dead once k_dec writes):
    char* xb = (char*)xrec;
    unsigned short* zh   = (unsigned short*)xb;                        // 4 MB
    unsigned short* zl   = (unsigned short*)(xb + (4u << 20));         // 4 MB
    unsigned short* eh   = (unsigned short*)(xb + (8u << 20));         // 256 KB
    unsigned short* el   = (unsigned short*)(xb + (8u << 20) + (NEMB * LD * 2)); // 256 KB
    float*          e2q  = (float*)(xb + (9u << 20));                  // 8 KB
    unsigned short* w1eh = (unsigned short*)(xb + (10u << 20));        // 32 KB
    unsigned short* w1em = w1eh + 16384;                               // 32 KB
    unsigned short* w1el = w1em + 16384;                               // 32 KB
    unsigned short* w2eh = w1el + 16384;                               // 8 KB
    unsigned short* w2em = w2eh + 4096;                                // 8 KB
    unsigned short* w2el = w2em + 4096;                                // 8 KB

    char* ws = (char*)d_ws;
    int*  count = (int*)ws;                                     // 4 B
    int*  idxA  = (int*)(ws + 16384);                           // 128 KB
    int*  list  = (int*)(ws + 147456);                          // 128 KB
    unsigned short* w1h = (unsigned short*)(ws + 278528);       // 8 KB
    unsigned short* w1l = (unsigned short*)(ws + 286720);       // 8 KB
    unsigned short* w2h = (unsigned short*)(ws + 294912);       // 32 KB
    unsigned short* w2l = (unsigned short*)(ws + 327680);       // 32 KB

    hipLaunchKernelGGL(k0_all,    dim3(168),        dim3(256), 0, stream,
                       emb, dw1, dw2, ew1, ew2, e2q, eh, el,
                       w1h, w1l, w2h, w2l, w1eh, w1em, w1el, w2eh, w2em, w2el, count);
    hipLaunchKernelGGL(k_enc,     dim3(BATCH / 64), dim3(256), 0, stream,
                       x, w1eh, w1em, w1el, eb1, w2eh, w2em, w2el, eb2, zE, zh, zl);
    hipLaunchKernelGGL(k2_mfma,   dim3(BATCH / 64), dim3(256), 0, stream,
                       zh, zl, eh, el, e2q, idxA, list, count);
    hipLaunchKernelGGL(k3_refine, dim3(128),        dim3(256), 0, stream,
                       zE, emb, count, list, idxA);
    hipLaunchKernelGGL(k_dec,     dim3(BATCH / 64), dim3(256), 0, stream,
                       idxA, emb, w1h, w1l, db1, w2h, w2l, db2, xrec, zQ);
}

// Round 18
// 127.323 us; speedup vs baseline: 1.0112x; 1.0042x over previous
//
#include <hip/hip_runtime.h>

#define BATCH   32768
#define SD      256
#define LD      64
#define HDIM    64
#define NEMB    2048
#define REFINE_THR_Q 5e-4f   // gap in q-units; s-gap = 2*q-gap -> 1e-3 effective

typedef short  short8 __attribute__((ext_vector_type(8)));
typedef float  f32x4  __attribute__((ext_vector_type(4)));

__device__ __forceinline__ unsigned short f2bf(float f) {
    unsigned int u = __float_as_uint(f);
    u = (u + 0x7FFFu + ((u >> 16) & 1u)) >> 16;
    return (unsigned short)u;
}
__device__ __forceinline__ float bf2f(unsigned short h) {
    return __uint_as_float(((unsigned int)h) << 16);
}

// ---------------------------------------------------------------------------
// K0 (merged): b 0..7   codebook e2q + 2-way split eh/el (+ count=0)
//              b 8..23  dec_w1 2-way split transposed [j][k]
//              b 24..87 dec_w2 2-way split transposed [j][k]
//              b 88..151 enc_w1 3-way split transposed [j(64)][k(256)]
//              b 152..167 enc_w2 3-way split transposed [j(64)][k(64)]
// ---------------------------------------------------------------------------
__global__ __launch_bounds__(256) void k0_all(const float* __restrict__ emb,
                                              const float* __restrict__ dw1,
                                              const float* __restrict__ dw2,
                                              const float* __restrict__ ew1,
                                              const float* __restrict__ ew2,
                                              float* __restrict__ e2q,
                                              unsigned short* __restrict__ eh,
                                              unsigned short* __restrict__ el,
                                              unsigned short* __restrict__ w1h,
                                              unsigned short* __restrict__ w1l,
                                              unsigned short* __restrict__ w2h,
                                              unsigned short* __restrict__ w2l,
                                              unsigned short* __restrict__ w1eh,
                                              unsigned short* __restrict__ w1em,
                                              unsigned short* __restrict__ w1el,
                                              unsigned short* __restrict__ w2eh,
                                              unsigned short* __restrict__ w2em,
                                              unsigned short* __restrict__ w2el,
                                              int* __restrict__ count) {
    int b = blockIdx.x;
    int t = threadIdx.x;
    if (b < 8) {
        int k = b * 256 + t;
        if (k == 0) *count = 0;
        const float* er = emb + (size_t)k * LD;
        unsigned short hrow[LD], lrow[LD];
        float s = 0.f;
#pragma unroll
        for (int q = 0; q < LD; ++q) {
            float v = er[q];
            s += v * v;
            unsigned short h = f2bf(v);
            hrow[q] = h;
            lrow[q] = f2bf(v - bf2f(h));
        }
        e2q[k] = -0.5f * s;
        short8* dh = (short8*)(eh + (size_t)k * LD);
        short8* dl = (short8*)(el + (size_t)k * LD);
#pragma unroll
        for (int q = 0; q < 8; ++q) {
            dh[q] = *(short8*)&hrow[q * 8];
            dl[q] = *(short8*)&lrow[q * 8];
        }
    } else if (b < 24) {
        int e = (b - 8) * 256 + t;
        int j = e >> 6, k = e & 63;
        float v = dw1[k * HDIM + j];
        unsigned short h = f2bf(v);
        w1h[e] = h; w1l[e] = f2bf(v - bf2f(h));
    } else if (b < 88) {
        int e = (b - 24) * 256 + t;
        int j = e >> 6, k = e & 63;
        float v = dw2[k * SD + j];
        unsigned short h = f2bf(v);
        w2h[e] = h; w2l[e] = f2bf(v - bf2f(h));
    } else if (b < 152) {
        int e = (b - 88) * 256 + t;      // [j][k]: j = e>>8, k = e&255
        int j = e >> 8, k = e & 255;
        float v = ew1[k * HDIM + j];
        unsigned short h = f2bf(v);
        float r1 = v - bf2f(h);
        unsigned short m = f2bf(r1);
        float r2 = r1 - bf2f(m);
        w1eh[e] = h; w1em[e] = m; w1el[e] = f2bf(r2);
    } else {
        int e = (b - 152) * 256 + t;     // [j][k]: j = e>>6, k = e&63
        int j = e >> 6, k = e & 63;
        float v = ew2[k * LD + j];
        unsigned short h = f2bf(v);
        float r1 = v - bf2f(h);
        unsigned short m = f2bf(r1);
        float r2 = r1 - bf2f(m);
        w2eh[e] = h; w2em[e] = m; w2el[e] = f2bf(r2);
    }
}

// ---------------------------------------------------------------------------
// ENC v7 (MFMA 6-term split; DYNAMIC kt loop like k2 so the 4 named weight
// triplets stay live across the back-edge -> real prefetch, not collapsed).
// Math order bit-identical to rounds 15-17.
// ---------------------------------------------------------------------------
#define MF(Afr, Bfr, C) __builtin_amdgcn_mfma_f32_16x16x32_bf16(Afr, Bfr, C, 0, 0, 0)

#define E_WLOAD(P, KT, JT) do {                                             \
    size_t wo_ = (size_t)((JT) * 16 + lo) * SD + (KT) * 32 + hi * 8;        \
    P##h = *(const short8*)(w1eh + wo_);                                    \
    P##m = *(const short8*)(w1em + wo_);                                    \
    P##l = *(const short8*)(w1el + wo_);                                    \
} while (0)

#define E_COMP(P, JT) do {                                                  \
    f32x4 c_ = c1[JT];                                                      \
    c_ = MF(xl8, P##h, c_);                                                 \
    c_ = MF(xm8, P##m, c_);                                                 \
    c_ = MF(xh8, P##l, c_);                                                 \
    c_ = MF(xm8, P##h, c_);                                                 \
    c_ = MF(xh8, P##m, c_);                                                 \
    c_ = MF(xh8, P##h, c_);                                                 \
    c1[JT] = c_;                                                            \
} while (0)

__global__ __launch_bounds__(256, 2) void k_enc(const float* __restrict__ x,
                                                const unsigned short* __restrict__ w1eh,
                                                const unsigned short* __restrict__ w1em,
                                                const unsigned short* __restrict__ w1el,
                                                const float* __restrict__ b1,
                                                const unsigned short* __restrict__ w2eh,
                                                const unsigned short* __restrict__ w2em,
                                                const unsigned short* __restrict__ w2el,
                                                const float* __restrict__ b2,
                                                float* __restrict__ zOut,
                                                unsigned short* __restrict__ zh,
                                                unsigned short* __restrict__ zl) {
    __shared__ float hds[4][16 * 68];
    int tid  = threadIdx.x;
    int lane = tid & 63;
    int w    = tid >> 6;
    int lo   = lane & 15;
    int hi   = lane >> 4;
    int rb   = blockIdx.x * 64 + w * 16;
    int row  = rb + lo;
    const float* xrow = x + (size_t)row * SD;

    // ---- layer 1: c1[jt] = x @ w1 + b1 over K=256
    f32x4 c1[4];
#pragma unroll
    for (int jt = 0; jt < 4; ++jt) {
        float bj = b1[jt * 16 + lo];
        f32x4 c = {bj, bj, bj, bj};
        c1[jt] = c;
    }

    short8 Ph, Pm, Pl, Qh, Qm, Ql, Rh, Rm, Rl, Sh, Sm, Sl;
    float4 xc0, xc1, xn0, xn1;
    xc0 = *(const float4*)(xrow + hi * 8);
    xc1 = *(const float4*)(xrow + hi * 8 + 4);
    E_WLOAD(P, 0, 0); E_WLOAD(Q, 0, 1); E_WLOAD(R, 0, 2); E_WLOAD(S, 0, 3);

#pragma unroll 1
    for (int kt = 0; kt < 8; ++kt) {
        int ktn = (kt + 1) & 7;            // wrap: last-iter loads are redundant, L2-hot
        xn0 = *(const float4*)(xrow + ktn * 32 + hi * 8);
        xn1 = *(const float4*)(xrow + ktn * 32 + hi * 8 + 4);

        // 3-way split of current x fragment
        float v[8] = {xc0.x, xc0.y, xc0.z, xc0.w, xc1.x, xc1.y, xc1.z, xc1.w};
        unsigned short sh[8], sm[8], sl[8];
#pragma unroll
        for (int q = 0; q < 8; ++q) {
            unsigned short h = f2bf(v[q]);
            float r1 = v[q] - bf2f(h);
            unsigned short m = f2bf(r1);
            float r2 = r1 - bf2f(m);
            sh[q] = h; sm[q] = m; sl[q] = f2bf(r2);
        }
        short8 xh8 = *(short8*)sh, xm8 = *(short8*)sm, xl8 = *(short8*)sl;

        E_COMP(P, 0); E_WLOAD(P, ktn, 0);
        E_COMP(Q, 1); E_WLOAD(Q, ktn, 1);
        E_COMP(R, 2); E_WLOAD(R, ktn, 2);
        E_COMP(S, 3); E_WLOAD(S, ktn, 3);
        xc0 = xn0; xc1 = xn1;
    }

    // relu -> per-wave LDS stripe (C layout: row=hi*4+r, col=jt*16+lo)
#pragma unroll
    for (int jt = 0; jt < 4; ++jt)
#pragma unroll
        for (int r = 0; r < 4; ++r)
            hds[w][(hi * 4 + r) * 68 + jt * 16 + lo] = fmaxf(c1[jt][r], 0.f);
    __syncthreads();

    // ---- layer 2: z = hd @ w2 + b2 over K=64 (weights hot in L2)
    f32x4 c2[4];
#pragma unroll
    for (int jt = 0; jt < 4; ++jt) {
        float bj = b2[jt * 16 + lo];
        f32x4 c = {bj, bj, bj, bj};
        c2[jt] = c;
    }
#pragma unroll
    for (int kt = 0; kt < 2; ++kt) {
        float4 a4 = *(const float4*)&hds[w][lo * 68 + kt * 32 + hi * 8];
        float4 b4 = *(const float4*)&hds[w][lo * 68 + kt * 32 + hi * 8 + 4];
        float v[8] = {a4.x, a4.y, a4.z, a4.w, b4.x, b4.y, b4.z, b4.w};
        unsigned short sh[8], sm[8], sl[8];
#pragma unroll
        for (int q = 0; q < 8; ++q) {
            unsigned short h = f2bf(v[q]);
            float r1 = v[q] - bf2f(h);
            unsigned short m = f2bf(r1);
            float r2 = r1 - bf2f(m);
            sh[q] = h; sm[q] = m; sl[q] = f2bf(r2);
        }
        short8 ah = *(short8*)sh, am = *(short8*)sm, al = *(short8*)sl;
#pragma unroll
        for (int jt = 0; jt < 4; ++jt) {
            size_t wo = (size_t)(jt * 16 + lo) * LD + kt * 32 + hi * 8;
            short8 bh8 = *(const short8*)(w2eh + wo);
            short8 bm8 = *(const short8*)(w2em + wo);
            short8 bl8 = *(const short8*)(w2el + wo);
            f32x4 c = c2[jt];
            c = MF(al, bh8, c);
            c = MF(am, bm8, c);
            c = MF(ah, bl8, c);
            c = MF(am, bh8, c);
            c = MF(ah, bm8, c);
            c = MF(ah, bh8, c);
            c2[jt] = c;
        }
    }
#pragma unroll
    for (int jt = 0; jt < 4; ++jt) {
#pragma unroll
        for (int r = 0; r < 4; ++r) {
            float z = c2[jt][r];
            size_t o = (size_t)(rb + hi * 4 + r) * LD + jt * 16 + lo;
            zOut[o] = z;
            unsigned short hb = f2bf(z);
            zh[o] = hb;
            zl[o] = f2bf(z - bf2f(hb));
        }
    }
}

// ---------------------------------------------------------------------------
// K2: MFMA split-bf16 screen (round-14 proven slim form).
// ---------------------------------------------------------------------------
#define K2_LOAD(P, t) do {                                                  \
    const unsigned short* ph_ = ehp + (size_t)(t) * 16 * LD;                \
    const unsigned short* pl_ = elp + (size_t)(t) * 16 * LD;                \
    P##a0 = *(const short8*)(ph_);                                          \
    P##a1 = *(const short8*)(ph_ + 32);                                     \
    P##a2 = *(const short8*)(pl_);                                          \
    P##a3 = *(const short8*)(pl_ + 32);                                     \
    P##e2 = *(const f32x4*)(e2q + cbase + (t) * 16 + hi * 4);               \
} while (0)

#define K2_COMP(P, t) do {                                                  \
    f32x4 acc_[4];                                                          \
    _Pragma("unroll")                                                       \
    for (int g = 0; g < 4; ++g) {                                           \
        f32x4 c_;                                                           \
        c_ = __builtin_amdgcn_mfma_f32_16x16x32_bf16(P##a0, bh[g][0], P##e2, 0, 0, 0); \
        c_ = __builtin_amdgcn_mfma_f32_16x16x32_bf16(P##a1, bh[g][1], c_, 0, 0, 0);    \
        c_ = __builtin_amdgcn_mfma_f32_16x16x32_bf16(P##a2, bh[g][0], c_, 0, 0, 0);    \
        c_ = __builtin_amdgcn_mfma_f32_16x16x32_bf16(P##a3, bh[g][1], c_, 0, 0, 0);    \
        c_ = __builtin_amdgcn_mfma_f32_16x16x32_bf16(P##a0, bl[g][0], c_, 0, 0, 0);    \
        c_ = __builtin_amdgcn_mfma_f32_16x16x32_bf16(P##a1, bl[g][1], c_, 0, 0, 0);    \
        acc_[g] = c_;                                                       \
    }                                                                       \
    _Pragma("unroll")                                                       \
    for (int g = 0; g < 4; ++g) {                                           \
        float m_ = fmaxf(fmaxf(acc_[g][0], acc_[g][1]),                     \
                         fmaxf(acc_[g][2], acc_[g][3]));                    \
        bool win_ = (m_ > bb[g]);                                           \
        qv[g] = win_ ? acc_[g] : qv[g];                                     \
        tt[g] = win_ ? (t) : tt[g];                                         \
        b2v[g] = fmaxf(b2v[g], fminf(bb[g], m_));                           \
        bb[g] = fmaxf(bb[g], m_);                                           \
    }                                                                       \
} while (0)

__global__ __launch_bounds__(256, 2) void k2_mfma(const unsigned short* __restrict__ zh,
                                                  const unsigned short* __restrict__ zl,
                                                  const unsigned short* __restrict__ eh,
                                                  const unsigned short* __restrict__ el,
                                                  const float* __restrict__ e2q,
                                                  int* __restrict__ idx,
                                                  int* __restrict__ list,
                                                  int* __restrict__ count) {
    int tid  = threadIdx.x;
    int lane = tid & 63;
    int w    = tid >> 6;
    int rb   = blockIdx.x * 64;
    int lo   = lane & 15;
    int hi   = lane >> 4;

    short8 bh[4][2], bl[4][2];
#pragma unroll
    for (int g = 0; g < 4; ++g) {
        size_t zo = (size_t)(rb + g * 16 + lo) * LD + hi * 8;
        bh[g][0] = *(const short8*)(zh + zo);
        bh[g][1] = *(const short8*)(zh + zo + 32);
        bl[g][0] = *(const short8*)(zl + zo);
        bl[g][1] = *(const short8*)(zl + zo + 32);
    }

    float bb[4], b2v[4];
    f32x4 qv[4];
    int   tt[4];
#pragma unroll
    for (int g = 0; g < 4; ++g) {
        bb[g] = -3.0e38f; b2v[g] = -3.0e38f; tt[g] = 0;
        qv[g][0] = qv[g][1] = qv[g][2] = qv[g][3] = -3.0e38f;
    }

    const int cbase = w * (NEMB / 4);
    const unsigned short* ehp = eh + (size_t)(cbase + lo) * LD + hi * 8;
    const unsigned short* elp = el + (size_t)(cbase + lo) * LD + hi * 8;

    short8 Aa0, Aa1, Aa2, Aa3; f32x4 Ae2;
    short8 Ba0, Ba1, Ba2, Ba3; f32x4 Be2;
    short8 Ca0, Ca1, Ca2, Ca3; f32x4 Ce2;

    K2_LOAD(A, 0);
    K2_LOAD(B, 1);
    K2_LOAD(C, 2);

    for (int tb = 0; tb < 27; tb += 3) {
        K2_COMP(A, tb);     K2_LOAD(A, tb + 3);
        K2_COMP(B, tb + 1); K2_LOAD(B, tb + 4);
        K2_COMP(C, tb + 2); K2_LOAD(C, tb + 5);
    }
    K2_COMP(A, 27); K2_LOAD(A, 30);
    K2_COMP(B, 28); K2_LOAD(B, 31);
    K2_COMP(C, 29);
    K2_COMP(A, 30);
    K2_COMP(B, 31);

    float ss[4];
    int   ii[4];
#pragma unroll
    for (int g = 0; g < 4; ++g) {
        float s0 = qv[g][0], s1 = qv[g][1], s2 = qv[g][2], s3 = qv[g][3];
        float M01 = fmaxf(s0, s1), L01 = fminf(s0, s1);
        float M23 = fmaxf(s2, s3), L23 = fminf(s2, s3);
        int   d01 = (s1 > s0) ? 1 : 0;
        int   d23 = (s3 > s2) ? 3 : 2;
        bool  cp  = (M23 > M01);
        float within2 = fmaxf(fminf(M01, M23), cp ? L23 : L01);
        int   dd  = cp ? d23 : d01;
        ii[g] = cbase + tt[g] * 16 + hi * 4 + dd;
        ss[g] = fmaxf(b2v[g], within2);
    }

#pragma unroll
    for (int off = 16; off <= 32; off <<= 1) {
#pragma unroll
        for (int g = 0; g < 4; ++g) {
            float ob = __shfl_xor(bb[g], off);
            float os = __shfl_xor(ss[g], off);
            int   oi = __shfl_xor(ii[g], off);
            ss[g] = fmaxf(fmaxf(fminf(bb[g], ob), os), ss[g]);
            ii[g] = (ob > bb[g]) ? oi : ii[g];
            bb[g] = fmaxf(bb[g], ob);
        }
    }

    __shared__ float Lb[4][64];
    __shared__ float Ls[4][64];
    __shared__ int   Li[4][64];
    if (lane < 16) {
#pragma unroll
        for (int g = 0; g < 4; ++g) {
            Lb[w][g * 16 + lane] = bb[g];
            Ls[w][g * 16 + lane] = ss[g];
            Li[w][g * 16 + lane] = ii[g];
        }
    }
    __syncthreads();

    if (tid < 64) {
        float B = Lb[0][tid], S = Ls[0][tid];
        int   I = Li[0][tid];
#pragma unroll
        for (int w2 = 1; w2 < 4; ++w2) {
            float ob = Lb[w2][tid], os = Ls[w2][tid];
            int   oi = Li[w2][tid];
            S = fmaxf(fmaxf(fminf(B, ob), os), S);
            I = (ob > B) ? oi : I;
            B = fmaxf(B, ob);
        }
        idx[rb + tid] = I;
        if (B - S < REFINE_THR_Q) {
            int p = atomicAdd(count, 1);
            list[p] = rb + tid;
        }
    }
}

// ---------------------------------------------------------------------------
// K3: exact f64 rescan of flagged near-tie rows (separate launch, proven).
// ---------------------------------------------------------------------------
__global__ __launch_bounds__(256) void k3_refine(const float* __restrict__ z,
                                                 const float* __restrict__ emb,
                                                 const int* __restrict__ count,
                                                 const int* __restrict__ list,
                                                 int* __restrict__ idx) {
    __shared__ double sv[256];
    __shared__ int    sx[256];
    int tid = threadIdx.x;
    int n = *count;
    for (int g = blockIdx.x; g < n; g += gridDim.x) {
        int row = list[g];
        const float4* zr4 = (const float4*)(z + (size_t)row * LD);
        float4 zv[16];
#pragma unroll
        for (int q = 0; q < 16; ++q) zv[q] = zr4[q];

        double best = 1.0e300;
        int bi = NEMB;
#pragma unroll 2
        for (int c = 0; c < 8; ++c) {
            int k = tid * 8 + c;
            const float4* er = (const float4*)(emb + (size_t)k * LD);
            double d0 = 0.0, d1 = 0.0, d2 = 0.0, d3 = 0.0;
#pragma unroll
            for (int q = 0; q < 16; ++q) {
                float4 e4 = er[q];
                double tx = (double)zv[q].x - (double)e4.x;
                double ty = (double)zv[q].y - (double)e4.y;
                double tz = (double)zv[q].z - (double)e4.z;
                double tw = (double)zv[q].w - (double)e4.w;
                d0 += tx * tx; d1 += ty * ty; d2 += tz * tz; d3 += tw * tw;
            }
            double d = (d0 + d1) + (d2 + d3);
            if (d < best) { best = d; bi = k; }
        }
        sv[tid] = best; sx[tid] = bi;
        __syncthreads();
        for (int s = 128; s > 0; s >>= 1) {
            if (tid < s) {
                if (sv[tid + s] < sv[tid] ||
                    (sv[tid + s] == sv[tid] && sx[tid + s] < sx[tid])) {
                    sv[tid] = sv[tid + s]; sx[tid] = sx[tid + s];
                }
            }
            __syncthreads();
        }
        if (tid == 0) idx[row] = sx[0];
        __syncthreads();
    }
}

// ---------------------------------------------------------------------------
// DEC v3 (MFMA split-bf16, 3 terms) — proven rounds 11-17.
// ---------------------------------------------------------------------------
__global__ __launch_bounds__(256, 2) void k_dec(const int* __restrict__ idx,
                                                const float* __restrict__ emb,
                                                const unsigned short* __restrict__ w1h,
                                                const unsigned short* __restrict__ w1l,
                                                const float* __restrict__ b1,
                                                const unsigned short* __restrict__ w2h,
                                                const unsigned short* __restrict__ w2l,
                                                const float* __restrict__ b2,
                                                float* __restrict__ xrec,
                                                float* __restrict__ zq) {
    __shared__ float hds[4][16 * 68];
    int tid  = threadIdx.x;
    int lane = tid & 63;
    int w    = tid >> 6;
    int lo   = lane & 15;
    int hi   = lane >> 4;
    int rb   = blockIdx.x * 64 + w * 16;
    int row  = rb + lo;
    int ix   = idx[row];

    short8 zah[2], zal[2];
    {
        const float* er  = emb + (size_t)ix * LD + hi * 8;
        float* zqr = zq + (size_t)row * LD + hi * 8;
#pragma unroll
        for (int kt = 0; kt < 2; ++kt) {
            float4 a = *(const float4*)(er + kt * 32);
            float4 b = *(const float4*)(er + kt * 32 + 4);
            *(float4*)(zqr + kt * 32) = a;
            *(float4*)(zqr + kt * 32 + 4) = b;
            float v[8] = {a.x, a.y, a.z, a.w, b.x, b.y, b.z, b.w};
            unsigned short hh[8], ll[8];
#pragma unroll
            for (int q = 0; q < 8; ++q) {
                unsigned short hb = f2bf(v[q]);
                hh[q] = hb;
                ll[q] = f2bf(v[q] - bf2f(hb));
            }
            zah[kt] = *(short8*)hh;
            zal[kt] = *(short8*)ll;
        }
    }

#pragma unroll
    for (int jt = 0; jt < 4; ++jt) {
        float bj = b1[jt * 16 + lo];
        f32x4 c = {bj, bj, bj, bj};
#pragma unroll
        for (int kt = 0; kt < 2; ++kt) {
            short8 bh8 = *(const short8*)(w1h + (jt * 16 + lo) * LD + kt * 32 + hi * 8);
            short8 bl8 = *(const short8*)(w1l + (jt * 16 + lo) * LD + kt * 32 + hi * 8);
            c = __builtin_amdgcn_mfma_f32_16x16x32_bf16(zah[kt], bh8, c, 0, 0, 0);
            c = __builtin_amdgcn_mfma_f32_16x16x32_bf16(zah[kt], bl8, c, 0, 0, 0);
            c = __builtin_amdgcn_mfma_f32_16x16x32_bf16(zal[kt], bh8, c, 0, 0, 0);
        }
#pragma unroll
        for (int r = 0; r < 4; ++r)
            hds[w][(hi * 4 + r) * 68 + jt * 16 + lo] = fmaxf(c[r], 0.f);
    }
    __syncthreads();

    short8 hah[2], hal[2];
#pragma unroll
    for (int kt = 0; kt < 2; ++kt) {
        float4 a = *(const float4*)&hds[w][lo * 68 + kt * 32 + hi * 8];
        float4 b = *(const float4*)&hds[w][lo * 68 + kt * 32 + hi * 8 + 4];
        float v[8] = {a.x, a.y, a.z, a.w, b.x, b.y, b.z, b.w};
        unsigned short hh[8], ll[8];
#pragma unroll
        for (int q = 0; q < 8; ++q) {
            unsigned short hb = f2bf(v[q]);
            hh[q] = hb;
            ll[q] = f2bf(v[q] - bf2f(hb));
        }
        hah[kt] = *(short8*)hh;
        hal[kt] = *(short8*)ll;
    }

    for (int jt = 0; jt < 16; ++jt) {
        float bj = b2[jt * 16 + lo];
        f32x4 c = {bj, bj, bj, bj};
#pragma unroll
        for (int kt = 0; kt < 2; ++kt) {
            short8 bh8 = *(const short8*)(w2h + (jt * 16 + lo) * LD + kt * 32 + hi * 8);
            short8 bl8 = *(const short8*)(w2l + (jt * 16 + lo) * LD + kt * 32 + hi * 8);
            c = __builtin_amdgcn_mfma_f32_16x16x32_bf16(hah[kt], bh8, c, 0, 0, 0);
            c = __builtin_amdgcn_mfma_f32_16x16x32_bf16(hah[kt], bl8, c, 0, 0, 0);
            c = __builtin_amdgcn_mfma_f32_16x16x32_bf16(hal[kt], bh8, c, 0, 0, 0);
        }
#pragma unroll
        for (int r = 0; r < 4; ++r)
            xrec[(size_t)(rb + hi * 4 + r) * SD + jt * 16 + lo] = c[r];
    }
}

// ---------------------------------------------------------------------------
extern "C" void kernel_launch(void* const* d_in, const int* in_sizes, int n_in,
                              void* d_out, int out_size, void* d_ws, size_t ws_size,
                              hipStream_t stream) {
    const float* x   = (const float*)d_in[0];
    const float* ew1 = (const float*)d_in[1];
    const float* eb1 = (const float*)d_in[2];
    const float* ew2 = (const float*)d_in[3];
    const float* eb2 = (const float*)d_in[4];
    const float* emb = (const float*)d_in[5];
    const float* dw1 = (const float*)d_in[6];
    const float* db1 = (const float*)d_in[7];
    const float* dw2 = (const float*)d_in[8];
    const float* db2 = (const float*)d_in[9];

    float* out  = (float*)d_out;
    float* xrec = out;                               // [B,256] (written LAST)
    float* zE   = out + (size_t)BATCH * SD;          // [B,64]
    float* zQ   = zE + (size_t)BATCH * LD;           // [B,64]

    // transient scratch inside the x_recon region (dead once k_dec writes):
    char* xb = (char*)xrec;
    unsigned short* zh   = (unsigned short*)xb;                        // 4 MB
    unsigned short* zl   = (unsigned short*)(xb + (4u << 20));         // 4 MB
    unsigned short* eh   = (unsigned short*)(xb + (8u << 20));         // 256 KB
    unsigned short* el   = (unsigned short*)(xb + (8u << 20) + (NEMB * LD * 2)); // 256 KB
    float*          e2q  = (float*)(xb + (9u << 20));                  // 8 KB
    unsigned short* w1eh = (unsigned short*)(xb + (10u << 20));        // 32 KB
    unsigned short* w1em = w1eh + 16384;                               // 32 KB
    unsigned short* w1el = w1em + 16384;                               // 32 KB
    unsigned short* w2eh = w1el + 16384;                               // 8 KB
    unsigned short* w2em = w2eh + 4096;                                // 8 KB
    unsigned short* w2el = w2em + 4096;                                // 8 KB

    char* ws = (char*)d_ws;
    int*  count = (int*)ws;                                     // 4 B
    int*  idxA  = (int*)(ws + 16384);                           // 128 KB
    int*  list  = (int*)(ws + 147456);                          // 128 KB
    unsigned short* w1h = (unsigned short*)(ws + 278528);       // 8 KB
    unsigned short* w1l = (unsigned short*)(ws + 286720);       // 8 KB
    unsigned short* w2h = (unsigned short*)(ws + 294912);       // 32 KB
    unsigned short* w2l = (unsigned short*)(ws + 327680);       // 32 KB

    hipLaunchKernelGGL(k0_all,    dim3(168),        dim3(256), 0, stream,
                       emb, dw1, dw2, ew1, ew2, e2q, eh, el,
                       w1h, w1l, w2h, w2l, w1eh, w1em, w1el, w2eh, w2em, w2el, count);
    hipLaunchKernelGGL(k_enc,     dim3(BATCH / 64), dim3(256), 0, stream,
                       x, w1eh, w1em, w1el, eb1, w2eh, w2em, w2el, eb2, zE, zh, zl);
    hipLaunchKernelGGL(k2_mfma,   dim3(BATCH / 64), dim3(256), 0, stream,
                       zh, zl, eh, el, e2q, idxA, list, count);
    hipLaunchKernelGGL(k3_refine, dim3(128),        dim3(256), 0, stream,
                       zE, emb, count, list, idxA);
    hipLaunchKernelGGL(k_dec,     dim3(BATCH / 64), dim3(256), 0, stream,
                       idxA, emb, w1h, w1l, db1, w2h, w2l, db2, xrec, zQ);
}

// Round 19
// 117.300 us; speedup vs baseline: 1.0976x; 1.0854x over previous
//
#include <hip/hip_runtime.h>

#define BATCH   32768
#define SD      256
#define LD      64
#define HDIM    64
#define NEMB    2048
#define REFINE_THR_Q 5e-4f   // gap in q-units; s-gap = 2*q-gap -> 1e-3 effective

typedef short  short8 __attribute__((ext_vector_type(8)));
typedef float  f32x4  __attribute__((ext_vector_type(4)));

__device__ __forceinline__ unsigned short f2bf(float f) {
    unsigned int u = __float_as_uint(f);
    u = (u + 0x7FFFu + ((u >> 16) & 1u)) >> 16;
    return (unsigned short)u;
}
__device__ __forceinline__ float bf2f(unsigned short h) {
    return __uint_as_float(((unsigned int)h) << 16);
}

// ---------------------------------------------------------------------------
// K0 (merged): b 0..7   codebook e2q + 2-way split eh/el (+ count=0)
//              b 8..23  dec_w1 2-way split transposed [j][k]
//              b 24..87 dec_w2 2-way split transposed [j][k]
//              b 88..151 enc_w1 3-way split PACKED [kt(8)][j(64)][kk(32)]
//              b 152..167 enc_w2 3-way split PACKED [kt(2)][j(64)][kk(32)]
// Packed layout => a wave's (kt,jt) fragment load covers contiguous 1KB.
// ---------------------------------------------------------------------------
__global__ __launch_bounds__(256) void k0_all(const float* __restrict__ emb,
                                              const float* __restrict__ dw1,
                                              const float* __restrict__ dw2,
                                              const float* __restrict__ ew1,
                                              const float* __restrict__ ew2,
                                              float* __restrict__ e2q,
                                              unsigned short* __restrict__ eh,
                                              unsigned short* __restrict__ el,
                                              unsigned short* __restrict__ w1h,
                                              unsigned short* __restrict__ w1l,
                                              unsigned short* __restrict__ w2h,
                                              unsigned short* __restrict__ w2l,
                                              unsigned short* __restrict__ w1eh,
                                              unsigned short* __restrict__ w1em,
                                              unsigned short* __restrict__ w1el,
                                              unsigned short* __restrict__ w2eh,
                                              unsigned short* __restrict__ w2em,
                                              unsigned short* __restrict__ w2el,
                                              int* __restrict__ count) {
    int b = blockIdx.x;
    int t = threadIdx.x;
    if (b < 8) {
        int k = b * 256 + t;
        if (k == 0) *count = 0;
        const float* er = emb + (size_t)k * LD;
        unsigned short hrow[LD], lrow[LD];
        float s = 0.f;
#pragma unroll
        for (int q = 0; q < LD; ++q) {
            float v = er[q];
            s += v * v;
            unsigned short h = f2bf(v);
            hrow[q] = h;
            lrow[q] = f2bf(v - bf2f(h));
        }
        e2q[k] = -0.5f * s;
        short8* dh = (short8*)(eh + (size_t)k * LD);
        short8* dl = (short8*)(el + (size_t)k * LD);
#pragma unroll
        for (int q = 0; q < 8; ++q) {
            dh[q] = *(short8*)&hrow[q * 8];
            dl[q] = *(short8*)&lrow[q * 8];
        }
    } else if (b < 24) {
        int e = (b - 8) * 256 + t;
        int j = e >> 6, k = e & 63;
        float v = dw1[k * HDIM + j];
        unsigned short h = f2bf(v);
        w1h[e] = h; w1l[e] = f2bf(v - bf2f(h));
    } else if (b < 88) {
        int e = (b - 24) * 256 + t;
        int j = e >> 6, k = e & 63;
        float v = dw2[k * SD + j];
        unsigned short h = f2bf(v);
        w2h[e] = h; w2l[e] = f2bf(v - bf2f(h));
    } else if (b < 152) {
        int e = (b - 88) * 256 + t;      // packed: kt = e>>11, j = (e&2047)>>5, kk = e&31
        int kt = e >> 11, j = (e & 2047) >> 5, kk = e & 31;
        int k = kt * 32 + kk;
        float v = ew1[k * HDIM + j];
        unsigned short h = f2bf(v);
        float r1 = v - bf2f(h);
        unsigned short m = f2bf(r1);
        float r2 = r1 - bf2f(m);
        w1eh[e] = h; w1em[e] = m; w1el[e] = f2bf(r2);
    } else {
        int e = (b - 152) * 256 + t;     // packed: kt = e>>11, j = (e&2047)>>5, kk = e&31
        int kt = e >> 11, j = (e & 2047) >> 5, kk = e & 31;
        int k = kt * 32 + kk;
        float v = ew2[k * LD + j];
        unsigned short h = f2bf(v);
        float r1 = v - bf2f(h);
        unsigned short m = f2bf(r1);
        float r2 = r1 - bf2f(m);
        w2eh[e] = h; w2em[e] = m; w2el[e] = f2bf(r2);
    }
}

// ---------------------------------------------------------------------------
// ENC v8 (MFMA 6-term split; PACKED weight layout -> coalesced 1KB fragment
// loads, k2-style). Dynamic kt loop retained. Math bit-identical to r15-18.
// ---------------------------------------------------------------------------
#define MF(Afr, Bfr, C) __builtin_amdgcn_mfma_f32_16x16x32_bf16(Afr, Bfr, C, 0, 0, 0)

#define E_WLOAD(P, KT, JT) do {                                             \
    size_t wo_ = (size_t)(KT) * 2048 + ((JT) * 16 + lo) * 32 + hi * 8;      \
    P##h = *(const short8*)(w1eh + wo_);                                    \
    P##m = *(const short8*)(w1em + wo_);                                    \
    P##l = *(const short8*)(w1el + wo_);                                    \
} while (0)

#define E_COMP(P, JT) do {                                                  \
    f32x4 c_ = c1[JT];                                                      \
    c_ = MF(xl8, P##h, c_);                                                 \
    c_ = MF(xm8, P##m, c_);                                                 \
    c_ = MF(xh8, P##l, c_);                                                 \
    c_ = MF(xm8, P##h, c_);                                                 \
    c_ = MF(xh8, P##m, c_);                                                 \
    c_ = MF(xh8, P##h, c_);                                                 \
    c1[JT] = c_;                                                            \
} while (0)

__global__ __launch_bounds__(256, 2) void k_enc(const float* __restrict__ x,
                                                const unsigned short* __restrict__ w1eh,
                                                const unsigned short* __restrict__ w1em,
                                                const unsigned short* __restrict__ w1el,
                                                const float* __restrict__ b1,
                                                const unsigned short* __restrict__ w2eh,
                                                const unsigned short* __restrict__ w2em,
                                                const unsigned short* __restrict__ w2el,
                                                const float* __restrict__ b2,
                                                float* __restrict__ zOut,
                                                unsigned short* __restrict__ zh,
                                                unsigned short* __restrict__ zl) {
    __shared__ float hds[4][16 * 68];
    int tid  = threadIdx.x;
    int lane = tid & 63;
    int w    = tid >> 6;
    int lo   = lane & 15;
    int hi   = lane >> 4;
    int rb   = blockIdx.x * 64 + w * 16;
    int row  = rb + lo;
    const float* xrow = x + (size_t)row * SD;

    // ---- layer 1: c1[jt] = x @ w1 + b1 over K=256
    f32x4 c1[4];
#pragma unroll
    for (int jt = 0; jt < 4; ++jt) {
        float bj = b1[jt * 16 + lo];
        f32x4 c = {bj, bj, bj, bj};
        c1[jt] = c;
    }

    short8 Ph, Pm, Pl, Qh, Qm, Ql, Rh, Rm, Rl, Sh, Sm, Sl;
    float4 xc0, xc1, xn0, xn1;
    xc0 = *(const float4*)(xrow + hi * 8);
    xc1 = *(const float4*)(xrow + hi * 8 + 4);
    E_WLOAD(P, 0, 0); E_WLOAD(Q, 0, 1); E_WLOAD(R, 0, 2); E_WLOAD(S, 0, 3);

#pragma unroll 1
    for (int kt = 0; kt < 8; ++kt) {
        int ktn = (kt + 1) & 7;            // wrap: last-iter loads redundant, L2-hot
        xn0 = *(const float4*)(xrow + ktn * 32 + hi * 8);
        xn1 = *(const float4*)(xrow + ktn * 32 + hi * 8 + 4);

        // 3-way split of current x fragment
        float v[8] = {xc0.x, xc0.y, xc0.z, xc0.w, xc1.x, xc1.y, xc1.z, xc1.w};
        unsigned short sh[8], sm[8], sl[8];
#pragma unroll
        for (int q = 0; q < 8; ++q) {
            unsigned short h = f2bf(v[q]);
            float r1 = v[q] - bf2f(h);
            unsigned short m = f2bf(r1);
            float r2 = r1 - bf2f(m);
            sh[q] = h; sm[q] = m; sl[q] = f2bf(r2);
        }
        short8 xh8 = *(short8*)sh, xm8 = *(short8*)sm, xl8 = *(short8*)sl;

        E_COMP(P, 0); E_WLOAD(P, ktn, 0);
        E_COMP(Q, 1); E_WLOAD(Q, ktn, 1);
        E_COMP(R, 2); E_WLOAD(R, ktn, 2);
        E_COMP(S, 3); E_WLOAD(S, ktn, 3);
        xc0 = xn0; xc1 = xn1;
    }

    // relu -> per-wave LDS stripe (C layout: row=hi*4+r, col=jt*16+lo)
#pragma unroll
    for (int jt = 0; jt < 4; ++jt)
#pragma unroll
        for (int r = 0; r < 4; ++r)
            hds[w][(hi * 4 + r) * 68 + jt * 16 + lo] = fmaxf(c1[jt][r], 0.f);
    __syncthreads();

    // ---- layer 2: z = hd @ w2 + b2 over K=64 (packed layout, L2-hot)
    f32x4 c2[4];
#pragma unroll
    for (int jt = 0; jt < 4; ++jt) {
        float bj = b2[jt * 16 + lo];
        f32x4 c = {bj, bj, bj, bj};
        c2[jt] = c;
    }
#pragma unroll
    for (int kt = 0; kt < 2; ++kt) {
        float4 a4 = *(const float4*)&hds[w][lo * 68 + kt * 32 + hi * 8];
        float4 b4 = *(const float4*)&hds[w][lo * 68 + kt * 32 + hi * 8 + 4];
        float v[8] = {a4.x, a4.y, a4.z, a4.w, b4.x, b4.y, b4.z, b4.w};
        unsigned short sh[8], sm[8], sl[8];
#pragma unroll
        for (int q = 0; q < 8; ++q) {
            unsigned short h = f2bf(v[q]);
            float r1 = v[q] - bf2f(h);
            unsigned short m = f2bf(r1);
            float r2 = r1 - bf2f(m);
            sh[q] = h; sm[q] = m; sl[q] = f2bf(r2);
        }
        short8 ah = *(short8*)sh, am = *(short8*)sm, al = *(short8*)sl;
#pragma unroll
        for (int jt = 0; jt < 4; ++jt) {
            size_t wo = (size_t)kt * 2048 + (jt * 16 + lo) * 32 + hi * 8;
            short8 bh8 = *(const short8*)(w2eh + wo);
            short8 bm8 = *(const short8*)(w2em + wo);
            short8 bl8 = *(const short8*)(w2el + wo);
            f32x4 c = c2[jt];
            c = MF(al, bh8, c);
            c = MF(am, bm8, c);
            c = MF(ah, bl8, c);
            c = MF(am, bh8, c);
            c = MF(ah, bm8, c);
            c = MF(ah, bh8, c);
            c2[jt] = c;
        }
    }
#pragma unroll
    for (int jt = 0; jt < 4; ++jt) {
#pragma unroll
        for (int r = 0; r < 4; ++r) {
            float z = c2[jt][r];
            size_t o = (size_t)(rb + hi * 4 + r) * LD + jt * 16 + lo;
            zOut[o] = z;
            unsigned short hb = f2bf(z);
            zh[o] = hb;
            zl[o] = f2bf(z - bf2f(hb));
        }
    }
}

// ---------------------------------------------------------------------------
// K2: MFMA split-bf16 screen (round-14 proven slim form).
// ---------------------------------------------------------------------------
#define K2_LOAD(P, t) do {                                                  \
    const unsigned short* ph_ = ehp + (size_t)(t) * 16 * LD;                \
    const unsigned short* pl_ = elp + (size_t)(t) * 16 * LD;                \
    P##a0 = *(const short8*)(ph_);                                          \
    P##a1 = *(const short8*)(ph_ + 32);                                     \
    P##a2 = *(const short8*)(pl_);                                          \
    P##a3 = *(const short8*)(pl_ + 32);                                     \
    P##e2 = *(const f32x4*)(e2q + cbase + (t) * 16 + hi * 4);               \
} while (0)

#define K2_COMP(P, t) do {                                                  \
    f32x4 acc_[4];                                                          \
    _Pragma("unroll")                                                       \
    for (int g = 0; g < 4; ++g) {                                           \
        f32x4 c_;                                                           \
        c_ = __builtin_amdgcn_mfma_f32_16x16x32_bf16(P##a0, bh[g][0], P##e2, 0, 0, 0); \
        c_ = __builtin_amdgcn_mfma_f32_16x16x32_bf16(P##a1, bh[g][1], c_, 0, 0, 0);    \
        c_ = __builtin_amdgcn_mfma_f32_16x16x32_bf16(P##a2, bh[g][0], c_, 0, 0, 0);    \
        c_ = __builtin_amdgcn_mfma_f32_16x16x32_bf16(P##a3, bh[g][1], c_, 0, 0, 0);    \
        c_ = __builtin_amdgcn_mfma_f32_16x16x32_bf16(P##a0, bl[g][0], c_, 0, 0, 0);    \
        c_ = __builtin_amdgcn_mfma_f32_16x16x32_bf16(P##a1, bl[g][1], c_, 0, 0, 0);    \
        acc_[g] = c_;                                                       \
    }                                                                       \
    _Pragma("unroll")                                                       \
    for (int g = 0; g < 4; ++g) {                                           \
        float m_ = fmaxf(fmaxf(acc_[g][0], acc_[g][1]),                     \
                         fmaxf(acc_[g][2], acc_[g][3]));                    \
        bool win_ = (m_ > bb[g]);                                           \
        qv[g] = win_ ? acc_[g] : qv[g];                                     \
        tt[g] = win_ ? (t) : tt[g];                                         \
        b2v[g] = fmaxf(b2v[g], fminf(bb[g], m_));                           \
        bb[g] = fmaxf(bb[g], m_);                                           \
    }                                                                       \
} while (0)

__global__ __launch_bounds__(256, 2) void k2_mfma(const unsigned short* __restrict__ zh,
                                                  const unsigned short* __restrict__ zl,
                                                  const unsigned short* __restrict__ eh,
                                                  const unsigned short* __restrict__ el,
                                                  const float* __restrict__ e2q,
                                                  int* __restrict__ idx,
                                                  int* __restrict__ list,
                                                  int* __restrict__ count) {
    int tid  = threadIdx.x;
    int lane = tid & 63;
    int w    = tid >> 6;
    int rb   = blockIdx.x * 64;
    int lo   = lane & 15;
    int hi   = lane >> 4;

    short8 bh[4][2], bl[4][2];
#pragma unroll
    for (int g = 0; g < 4; ++g) {
        size_t zo = (size_t)(rb + g * 16 + lo) * LD + hi * 8;
        bh[g][0] = *(const short8*)(zh + zo);
        bh[g][1] = *(const short8*)(zh + zo + 32);
        bl[g][0] = *(const short8*)(zl + zo);
        bl[g][1] = *(const short8*)(zl + zo + 32);
    }

    float bb[4], b2v[4];
    f32x4 qv[4];
    int   tt[4];
#pragma unroll
    for (int g = 0; g < 4; ++g) {
        bb[g] = -3.0e38f; b2v[g] = -3.0e38f; tt[g] = 0;
        qv[g][0] = qv[g][1] = qv[g][2] = qv[g][3] = -3.0e38f;
    }

    const int cbase = w * (NEMB / 4);
    const unsigned short* ehp = eh + (size_t)(cbase + lo) * LD + hi * 8;
    const unsigned short* elp = el + (size_t)(cbase + lo) * LD + hi * 8;

    short8 Aa0, Aa1, Aa2, Aa3; f32x4 Ae2;
    short8 Ba0, Ba1, Ba2, Ba3; f32x4 Be2;
    short8 Ca0, Ca1, Ca2, Ca3; f32x4 Ce2;

    K2_LOAD(A, 0);
    K2_LOAD(B, 1);
    K2_LOAD(C, 2);

    for (int tb = 0; tb < 27; tb += 3) {
        K2_COMP(A, tb);     K2_LOAD(A, tb + 3);
        K2_COMP(B, tb + 1); K2_LOAD(B, tb + 4);
        K2_COMP(C, tb + 2); K2_LOAD(C, tb + 5);
    }
    K2_COMP(A, 27); K2_LOAD(A, 30);
    K2_COMP(B, 28); K2_LOAD(B, 31);
    K2_COMP(C, 29);
    K2_COMP(A, 30);
    K2_COMP(B, 31);

    float ss[4];
    int   ii[4];
#pragma unroll
    for (int g = 0; g < 4; ++g) {
        float s0 = qv[g][0], s1 = qv[g][1], s2 = qv[g][2], s3 = qv[g][3];
        float M01 = fmaxf(s0, s1), L01 = fminf(s0, s1);
        float M23 = fmaxf(s2, s3), L23 = fminf(s2, s3);
        int   d01 = (s1 > s0) ? 1 : 0;
        int   d23 = (s3 > s2) ? 3 : 2;
        bool  cp  = (M23 > M01);
        float within2 = fmaxf(fminf(M01, M23), cp ? L23 : L01);
        int   dd  = cp ? d23 : d01;
        ii[g] = cbase + tt[g] * 16 + hi * 4 + dd;
        ss[g] = fmaxf(b2v[g], within2);
    }

#pragma unroll
    for (int off = 16; off <= 32; off <<= 1) {
#pragma unroll
        for (int g = 0; g < 4; ++g) {
            float ob = __shfl_xor(bb[g], off);
            float os = __shfl_xor(ss[g], off);
            int   oi = __shfl_xor(ii[g], off);
            ss[g] = fmaxf(fmaxf(fminf(bb[g], ob), os), ss[g]);
            ii[g] = (ob > bb[g]) ? oi : ii[g];
            bb[g] = fmaxf(bb[g], ob);
        }
    }

    __shared__ float Lb[4][64];
    __shared__ float Ls[4][64];
    __shared__ int   Li[4][64];
    if (lane < 16) {
#pragma unroll
        for (int g = 0; g < 4; ++g) {
            Lb[w][g * 16 + lane] = bb[g];
            Ls[w][g * 16 + lane] = ss[g];
            Li[w][g * 16 + lane] = ii[g];
        }
    }
    __syncthreads();

    if (tid < 64) {
        float B = Lb[0][tid], S = Ls[0][tid];
        int   I = Li[0][tid];
#pragma unroll
        for (int w2 = 1; w2 < 4; ++w2) {
            float ob = Lb[w2][tid], os = Ls[w2][tid];
            int   oi = Li[w2][tid];
            S = fmaxf(fmaxf(fminf(B, ob), os), S);
            I = (ob > B) ? oi : I;
            B = fmaxf(B, ob);
        }
        idx[rb + tid] = I;
        if (B - S < REFINE_THR_Q) {
            int p = atomicAdd(count, 1);
            list[p] = rb + tid;
        }
    }
}

// ---------------------------------------------------------------------------
// K3: exact f64 rescan of flagged near-tie rows (separate launch, proven).
// ---------------------------------------------------------------------------
__global__ __launch_bounds__(256) void k3_refine(const float* __restrict__ z,
                                                 const float* __restrict__ emb,
                                                 const int* __restrict__ count,
                                                 const int* __restrict__ list,
                                                 int* __restrict__ idx) {
    __shared__ double sv[256];
    __shared__ int    sx[256];
    int tid = threadIdx.x;
    int n = *count;
    for (int g = blockIdx.x; g < n; g += gridDim.x) {
        int row = list[g];
        const float4* zr4 = (const float4*)(z + (size_t)row * LD);
        float4 zv[16];
#pragma unroll
        for (int q = 0; q < 16; ++q) zv[q] = zr4[q];

        double best = 1.0e300;
        int bi = NEMB;
#pragma unroll 2
        for (int c = 0; c < 8; ++c) {
            int k = tid * 8 + c;
            const float4* er = (const float4*)(emb + (size_t)k * LD);
            double d0 = 0.0, d1 = 0.0, d2 = 0.0, d3 = 0.0;
#pragma unroll
            for (int q = 0; q < 16; ++q) {
                float4 e4 = er[q];
                double tx = (double)zv[q].x - (double)e4.x;
                double ty = (double)zv[q].y - (double)e4.y;
                double tz = (double)zv[q].z - (double)e4.z;
                double tw = (double)zv[q].w - (double)e4.w;
                d0 += tx * tx; d1 += ty * ty; d2 += tz * tz; d3 += tw * tw;
            }
            double d = (d0 + d1) + (d2 + d3);
            if (d < best) { best = d; bi = k; }
        }
        sv[tid] = best; sx[tid] = bi;
        __syncthreads();
        for (int s = 128; s > 0; s >>= 1) {
            if (tid < s) {
                if (sv[tid + s] < sv[tid] ||
                    (sv[tid + s] == sv[tid] && sx[tid + s] < sx[tid])) {
                    sv[tid] = sv[tid + s]; sx[tid] = sx[tid + s];
                }
            }
            __syncthreads();
        }
        if (tid == 0) idx[row] = sx[0];
        __syncthreads();
    }
}

// ---------------------------------------------------------------------------
// DEC v3 (MFMA split-bf16, 3 terms) — proven rounds 11-18.
// ---------------------------------------------------------------------------
__global__ __launch_bounds__(256, 2) void k_dec(const int* __restrict__ idx,
                                                const float* __restrict__ emb,
                                                const unsigned short* __restrict__ w1h,
                                                const unsigned short* __restrict__ w1l,
                                                const float* __restrict__ b1,
                                                const unsigned short* __restrict__ w2h,
                                                const unsigned short* __restrict__ w2l,
                                                const float* __restrict__ b2,
                                                float* __restrict__ xrec,
                                                float* __restrict__ zq) {
    __shared__ float hds[4][16 * 68];
    int tid  = threadIdx.x;
    int lane = tid & 63;
    int w    = tid >> 6;
    int lo   = lane & 15;
    int hi   = lane >> 4;
    int rb   = blockIdx.x * 64 + w * 16;
    int row  = rb + lo;
    int ix   = idx[row];

    short8 zah[2], zal[2];
    {
        const float* er  = emb + (size_t)ix * LD + hi * 8;
        float* zqr = zq + (size_t)row * LD + hi * 8;
#pragma unroll
        for (int kt = 0; kt < 2; ++kt) {
            float4 a = *(const float4*)(er + kt * 32);
            float4 b = *(const float4*)(er + kt * 32 + 4);
            *(float4*)(zqr + kt * 32) = a;
            *(float4*)(zqr + kt * 32 + 4) = b;
            float v[8] = {a.x, a.y, a.z, a.w, b.x, b.y, b.z, b.w};
            unsigned short hh[8], ll[8];
#pragma unroll
            for (int q = 0; q < 8; ++q) {
                unsigned short hb = f2bf(v[q]);
                hh[q] = hb;
                ll[q] = f2bf(v[q] - bf2f(hb));
            }
            zah[kt] = *(short8*)hh;
            zal[kt] = *(short8*)ll;
        }
    }

#pragma unroll
    for (int jt = 0; jt < 4; ++jt) {
        float bj = b1[jt * 16 + lo];
        f32x4 c = {bj, bj, bj, bj};
#pragma unroll
        for (int kt = 0; kt < 2; ++kt) {
            short8 bh8 = *(const short8*)(w1h + (jt * 16 + lo) * LD + kt * 32 + hi * 8);
            short8 bl8 = *(const short8*)(w1l + (jt * 16 + lo) * LD + kt * 32 + hi * 8);
            c = __builtin_amdgcn_mfma_f32_16x16x32_bf16(zah[kt], bh8, c, 0, 0, 0);
            c = __builtin_amdgcn_mfma_f32_16x16x32_bf16(zah[kt], bl8, c, 0, 0, 0);
            c = __builtin_amdgcn_mfma_f32_16x16x32_bf16(zal[kt], bh8, c, 0, 0, 0);
        }
#pragma unroll
        for (int r = 0; r < 4; ++r)
            hds[w][(hi * 4 + r) * 68 + jt * 16 + lo] = fmaxf(c[r], 0.f);
    }
    __syncthreads();

    short8 hah[2], hal[2];
#pragma unroll
    for (int kt = 0; kt < 2; ++kt) {
        float4 a = *(const float4*)&hds[w][lo * 68 + kt * 32 + hi * 8];
        float4 b = *(const float4*)&hds[w][lo * 68 + kt * 32 + hi * 8 + 4];
        float v[8] = {a.x, a.y, a.z, a.w, b.x, b.y, b.z, b.w};
        unsigned short hh[8], ll[8];
#pragma unroll
        for (int q = 0; q < 8; ++q) {
            unsigned short hb = f2bf(v[q]);
            hh[q] = hb;
            ll[q] = f2bf(v[q] - bf2f(hb));
        }
        hah[kt] = *(short8*)hh;
        hal[kt] = *(short8*)ll;
    }

    for (int jt = 0; jt < 16; ++jt) {
        float bj = b2[jt * 16 + lo];
        f32x4 c = {bj, bj, bj, bj};
#pragma unroll
        for (int kt = 0; kt < 2; ++kt) {
            short8 bh8 = *(const short8*)(w2h + (jt * 16 + lo) * LD + kt * 32 + hi * 8);
            short8 bl8 = *(const short8*)(w2l + (jt * 16 + lo) * LD + kt * 32 + hi * 8);
            c = __builtin_amdgcn_mfma_f32_16x16x32_bf16(hah[kt], bh8, c, 0, 0, 0);
            c = __builtin_amdgcn_mfma_f32_16x16x32_bf16(hah[kt], bl8, c, 0, 0, 0);
            c = __builtin_amdgcn_mfma_f32_16x16x32_bf16(hal[kt], bh8, c, 0, 0, 0);
        }
#pragma unroll
        for (int r = 0; r < 4; ++r)
            xrec[(size_t)(rb + hi * 4 + r) * SD + jt * 16 + lo] = c[r];
    }
}

// ---------------------------------------------------------------------------
extern "C" void kernel_launch(void* const* d_in, const int* in_sizes, int n_in,
                              void* d_out, int out_size, void* d_ws, size_t ws_size,
                              hipStream_t stream) {
    const float* x   = (const float*)d_in[0];
    const float* ew1 = (const float*)d_in[1];
    const float* eb1 = (const float*)d_in[2];
    const float* ew2 = (const float*)d_in[3];
    const float* eb2 = (const float*)d_in[4];
    const float* emb = (const float*)d_in[5];
    const float* dw1 = (const float*)d_in[6];
    const float* db1 = (const float*)d_in[7];
    const float* dw2 = (const float*)d_in[8];
    const float* db2 = (const float*)d_in[9];

    float* out  = (float*)d_out;
    float* xrec = out;                               // [B,256] (written LAST)
    float* zE   = out + (size_t)BATCH * SD;          // [B,64]
    float* zQ   = zE + (size_t)BATCH * LD;           // [B,64]

    // transient scratch inside the x_recon region (dead once k_dec writes):
    char* xb = (char*)xrec;
    unsigned short* zh   = (unsigned short*)xb;                        // 4 MB
    unsigned short* zl   = (unsigned short*)(xb + (4u << 20));         // 4 MB
    unsigned short* eh   = (unsigned short*)(xb + (8u << 20));         // 256 KB
    unsigned short* el   = (unsigned short*)(xb + (8u << 20) + (NEMB * LD * 2)); // 256 KB
    float*          e2q  = (float*)(xb + (9u << 20));                  // 8 KB
    unsigned short* w1eh = (unsigned short*)(xb + (10u << 20));        // 32 KB
    unsigned short* w1em = w1eh + 16384;                               // 32 KB
    unsigned short* w1el = w1em + 16384;                               // 32 KB
    unsigned short* w2eh = w1el + 16384;                               // 8 KB
    unsigned short* w2em = w2eh + 4096;                                // 8 KB
    unsigned short* w2el = w2em + 4096;                                // 8 KB

    char* ws = (char*)d_ws;
    int*  count = (int*)ws;                                     // 4 B
    int*  idxA  = (int*)(ws + 16384);                           // 128 KB
    int*  list  = (int*)(ws + 147456);                          // 128 KB
    unsigned short* w1h = (unsigned short*)(ws + 278528);       // 8 KB
    unsigned short* w1l = (unsigned short*)(ws + 286720);       // 8 KB
    unsigned short* w2h = (unsigned short*)(ws + 294912);       // 32 KB
    unsigned short* w2l = (unsigned short*)(ws + 327680);       // 32 KB

    hipLaunchKernelGGL(k0_all,    dim3(168),        dim3(256), 0, stream,
                       emb, dw1, dw2, ew1, ew2, e2q, eh, el,
                       w1h, w1l, w2h, w2l, w1eh, w1em, w1el, w2eh, w2em, w2el, count);
    hipLaunchKernelGGL(k_enc,     dim3(BATCH / 64), dim3(256), 0, stream,
                       x, w1eh, w1em, w1el, eb1, w2eh, w2em, w2el, eb2, zE, zh, zl);
    hipLaunchKernelGGL(k2_mfma,   dim3(BATCH / 64), dim3(256), 0, stream,
                       zh, zl, eh, el, e2q, idxA, list, count);
    hipLaunchKernelGGL(k3_refine, dim3(128),        dim3(256), 0, stream,
                       zE, emb, count, list, idxA);
    hipLaunchKernelGGL(k_dec,     dim3(BATCH / 64), dim3(256), 0, stream,
                       idxA, emb, w1h, w1l, db1, w2h, w2l, db2, xrec, zQ);
}

// Round 20
// 110.875 us; speedup vs baseline: 1.1612x; 1.0579x over previous
//
#include <hip/hip_runtime.h>

#define BATCH   32768
#define SD      256
#define LD      64
#define HDIM    64
#define NEMB    2048
#define REFINE_THR_Q 5e-4f   // gap in q-units; s-gap = 2*q-gap -> 1e-3 effective

typedef short  short8 __attribute__((ext_vector_type(8)));
typedef float  f32x4  __attribute__((ext_vector_type(4)));

__device__ __forceinline__ unsigned short f2bf(float f) {
    unsigned int u = __float_as_uint(f);
    u = (u + 0x7FFFu + ((u >> 16) & 1u)) >> 16;
    return (unsigned short)u;
}
__device__ __forceinline__ float bf2f(unsigned short h) {
    return __uint_as_float(((unsigned int)h) << 16);
}

// ---------------------------------------------------------------------------
// K0 (merged): b 0..7   codebook e2q + 2-way split eh/el (+ count=0)
//              b 8..23  dec_w1 2-way split transposed [j][k]
//              b 24..87 dec_w2 2-way split transposed [j][k]
//              b 88..151 enc_w1 3-way split PACKED [kt(8)][j(64)][kk(32)]
//              b 152..167 enc_w2 3-way split PACKED [kt(2)][j(64)][kk(32)]
// ---------------------------------------------------------------------------
__global__ __launch_bounds__(256) void k0_all(const float* __restrict__ emb,
                                              const float* __restrict__ dw1,
                                              const float* __restrict__ dw2,
                                              const float* __restrict__ ew1,
                                              const float* __restrict__ ew2,
                                              float* __restrict__ e2q,
                                              unsigned short* __restrict__ eh,
                                              unsigned short* __restrict__ el,
                                              unsigned short* __restrict__ w1h,
                                              unsigned short* __restrict__ w1l,
                                              unsigned short* __restrict__ w2h,
                                              unsigned short* __restrict__ w2l,
                                              unsigned short* __restrict__ w1eh,
                                              unsigned short* __restrict__ w1em,
                                              unsigned short* __restrict__ w1el,
                                              unsigned short* __restrict__ w2eh,
                                              unsigned short* __restrict__ w2em,
                                              unsigned short* __restrict__ w2el,
                                              int* __restrict__ count) {
    int b = blockIdx.x;
    int t = threadIdx.x;
    if (b < 8) {
        int k = b * 256 + t;
        if (k == 0) *count = 0;
        const float* er = emb + (size_t)k * LD;
        unsigned short hrow[LD], lrow[LD];
        float s = 0.f;
#pragma unroll
        for (int q = 0; q < LD; ++q) {
            float v = er[q];
            s += v * v;
            unsigned short h = f2bf(v);
            hrow[q] = h;
            lrow[q] = f2bf(v - bf2f(h));
        }
        e2q[k] = -0.5f * s;
        short8* dh = (short8*)(eh + (size_t)k * LD);
        short8* dl = (short8*)(el + (size_t)k * LD);
#pragma unroll
        for (int q = 0; q < 8; ++q) {
            dh[q] = *(short8*)&hrow[q * 8];
            dl[q] = *(short8*)&lrow[q * 8];
        }
    } else if (b < 24) {
        int e = (b - 8) * 256 + t;
        int j = e >> 6, k = e & 63;
        float v = dw1[k * HDIM + j];
        unsigned short h = f2bf(v);
        w1h[e] = h; w1l[e] = f2bf(v - bf2f(h));
    } else if (b < 88) {
        int e = (b - 24) * 256 + t;
        int j = e >> 6, k = e & 63;
        float v = dw2[k * SD + j];
        unsigned short h = f2bf(v);
        w2h[e] = h; w2l[e] = f2bf(v - bf2f(h));
    } else if (b < 152) {
        int e = (b - 88) * 256 + t;      // packed: kt = e>>11, j = (e&2047)>>5, kk = e&31
        int kt = e >> 11, j = (e & 2047) >> 5, kk = e & 31;
        int k = kt * 32 + kk;
        float v = ew1[k * HDIM + j];
        unsigned short h = f2bf(v);
        float r1 = v - bf2f(h);
        unsigned short m = f2bf(r1);
        float r2 = r1 - bf2f(m);
        w1eh[e] = h; w1em[e] = m; w1el[e] = f2bf(r2);
    } else {
        int e = (b - 152) * 256 + t;
        int kt = e >> 11, j = (e & 2047) >> 5, kk = e & 31;
        int k = kt * 32 + kk;
        float v = ew2[k * LD + j];
        unsigned short h = f2bf(v);
        float r1 = v - bf2f(h);
        unsigned short m = f2bf(r1);
        float r2 = r1 - bf2f(m);
        w2eh[e] = h; w2em[e] = m; w2el[e] = f2bf(r2);
    }
}

// ---------------------------------------------------------------------------
// K_FUSED = ENC v8 (packed-weight MFMA 6-term split, proven r19)
//           + LDS handoff of zh/zl ([64][68] bf16, conflict-free)
//           + K2 scan (round-14 proven slim form).
// Same math as r19 (bit-identical); zh/zl never touch global.
// ---------------------------------------------------------------------------
#define MF(Afr, Bfr, C) __builtin_amdgcn_mfma_f32_16x16x32_bf16(Afr, Bfr, C, 0, 0, 0)

#define E_WLOAD(P, KT, JT) do {                                             \
    size_t wo_ = (size_t)(KT) * 2048 + ((JT) * 16 + lo) * 32 + hi * 8;      \
    P##h = *(const short8*)(w1eh + wo_);                                    \
    P##m = *(const short8*)(w1em + wo_);                                    \
    P##l = *(const short8*)(w1el + wo_);                                    \
} while (0)

#define E_COMP(P, JT) do {                                                  \
    f32x4 c_ = c1[JT];                                                      \
    c_ = MF(xl8, P##h, c_);                                                 \
    c_ = MF(xm8, P##m, c_);                                                 \
    c_ = MF(xh8, P##l, c_);                                                 \
    c_ = MF(xm8, P##h, c_);                                                 \
    c_ = MF(xh8, P##m, c_);                                                 \
    c_ = MF(xh8, P##h, c_);                                                 \
    c1[JT] = c_;                                                            \
} while (0)

#define K2_LOAD(P, t) do {                                                  \
    const unsigned short* ph_ = ehp + (size_t)(t) * 16 * LD;                \
    const unsigned short* pl_ = elp + (size_t)(t) * 16 * LD;                \
    P##a0 = *(const short8*)(ph_);                                          \
    P##a1 = *(const short8*)(ph_ + 32);                                     \
    P##a2 = *(const short8*)(pl_);                                          \
    P##a3 = *(const short8*)(pl_ + 32);                                     \
    P##e2 = *(const f32x4*)(e2q + cbase + (t) * 16 + hi * 4);               \
} while (0)

#define K2_COMP(P, t) do {                                                  \
    f32x4 acc_[4];                                                          \
    _Pragma("unroll")                                                       \
    for (int g = 0; g < 4; ++g) {                                           \
        f32x4 c_;                                                           \
        c_ = __builtin_amdgcn_mfma_f32_16x16x32_bf16(P##a0, bh[g][0], P##e2, 0, 0, 0); \
        c_ = __builtin_amdgcn_mfma_f32_16x16x32_bf16(P##a1, bh[g][1], c_, 0, 0, 0);    \
        c_ = __builtin_amdgcn_mfma_f32_16x16x32_bf16(P##a2, bh[g][0], c_, 0, 0, 0);    \
        c_ = __builtin_amdgcn_mfma_f32_16x16x32_bf16(P##a3, bh[g][1], c_, 0, 0, 0);    \
        c_ = __builtin_amdgcn_mfma_f32_16x16x32_bf16(P##a0, bl[g][0], c_, 0, 0, 0);    \
        c_ = __builtin_amdgcn_mfma_f32_16x16x32_bf16(P##a1, bl[g][1], c_, 0, 0, 0);    \
        acc_[g] = c_;                                                       \
    }                                                                       \
    _Pragma("unroll")                                                       \
    for (int g = 0; g < 4; ++g) {                                           \
        float m_ = fmaxf(fmaxf(acc_[g][0], acc_[g][1]),                     \
                         fmaxf(acc_[g][2], acc_[g][3]));                    \
        bool win_ = (m_ > bb[g]);                                           \
        qv[g] = win_ ? acc_[g] : qv[g];                                     \
        tt[g] = win_ ? (t) : tt[g];                                         \
        b2v[g] = fmaxf(b2v[g], fminf(bb[g], m_));                           \
        bb[g] = fmaxf(bb[g], m_);                                           \
    }                                                                       \
} while (0)

__global__ __launch_bounds__(256, 2) void k_fused(const float* __restrict__ x,
                                                  const unsigned short* __restrict__ w1eh,
                                                  const unsigned short* __restrict__ w1em,
                                                  const unsigned short* __restrict__ w1el,
                                                  const float* __restrict__ b1,
                                                  const unsigned short* __restrict__ w2eh,
                                                  const unsigned short* __restrict__ w2em,
                                                  const unsigned short* __restrict__ w2el,
                                                  const float* __restrict__ b2,
                                                  const unsigned short* __restrict__ eh,
                                                  const unsigned short* __restrict__ el,
                                                  const float* __restrict__ e2q,
                                                  float* __restrict__ zOut,
                                                  int* __restrict__ idx,
                                                  int* __restrict__ list,
                                                  int* __restrict__ count) {
    __shared__ float hds[4][16 * 68];        // 17408 B; re-used as zls after L2
    unsigned short* zlsH = (unsigned short*)hds;            // [64][68] bf16
    unsigned short* zlsL = (unsigned short*)hds + 64 * 68;  // [64][68] bf16
    __shared__ float Lb[4][64];
    __shared__ float Ls[4][64];
    __shared__ int   Li[4][64];

    int tid  = threadIdx.x;
    int lane = tid & 63;
    int w    = tid >> 6;
    int lo   = lane & 15;
    int hi   = lane >> 4;
    int rb   = blockIdx.x * 64;
    int rbw  = rb + w * 16;
    int row  = rbw + lo;
    const float* xrow = x + (size_t)row * SD;

    // ============================ ENC phase ============================
    // ---- layer 1: c1[jt] = x @ w1 + b1 over K=256
    f32x4 c1[4];
#pragma unroll
    for (int jt = 0; jt < 4; ++jt) {
        float bj = b1[jt * 16 + lo];
        f32x4 c = {bj, bj, bj, bj};
        c1[jt] = c;
    }

    short8 Ph, Pm, Pl, Qh, Qm, Ql, Rh, Rm, Rl, Sh, Sm, Sl;
    float4 xc0, xc1, xn0, xn1;
    xc0 = *(const float4*)(xrow + hi * 8);
    xc1 = *(const float4*)(xrow + hi * 8 + 4);
    E_WLOAD(P, 0, 0); E_WLOAD(Q, 0, 1); E_WLOAD(R, 0, 2); E_WLOAD(S, 0, 3);

#pragma unroll 1
    for (int kt = 0; kt < 8; ++kt) {
        int ktn = (kt + 1) & 7;
        xn0 = *(const float4*)(xrow + ktn * 32 + hi * 8);
        xn1 = *(const float4*)(xrow + ktn * 32 + hi * 8 + 4);

        float v[8] = {xc0.x, xc0.y, xc0.z, xc0.w, xc1.x, xc1.y, xc1.z, xc1.w};
        unsigned short sh[8], sm[8], sl[8];
#pragma unroll
        for (int q = 0; q < 8; ++q) {
            unsigned short h = f2bf(v[q]);
            float r1 = v[q] - bf2f(h);
            unsigned short m = f2bf(r1);
            float r2 = r1 - bf2f(m);
            sh[q] = h; sm[q] = m; sl[q] = f2bf(r2);
        }
        short8 xh8 = *(short8*)sh, xm8 = *(short8*)sm, xl8 = *(short8*)sl;

        E_COMP(P, 0); E_WLOAD(P, ktn, 0);
        E_COMP(Q, 1); E_WLOAD(Q, ktn, 1);
        E_COMP(R, 2); E_WLOAD(R, ktn, 2);
        E_COMP(S, 3); E_WLOAD(S, ktn, 3);
        xc0 = xn0; xc1 = xn1;
    }

    // relu -> per-wave LDS stripe
#pragma unroll
    for (int jt = 0; jt < 4; ++jt)
#pragma unroll
        for (int r = 0; r < 4; ++r)
            hds[w][(hi * 4 + r) * 68 + jt * 16 + lo] = fmaxf(c1[jt][r], 0.f);
    __syncthreads();

    // ---- layer 2: z = hd @ w2 + b2 over K=64
    f32x4 c2[4];
#pragma unroll
    for (int jt = 0; jt < 4; ++jt) {
        float bj = b2[jt * 16 + lo];
        f32x4 c = {bj, bj, bj, bj};
        c2[jt] = c;
    }
#pragma unroll
    for (int kt = 0; kt < 2; ++kt) {
        float4 a4 = *(const float4*)&hds[w][lo * 68 + kt * 32 + hi * 8];
        float4 b4 = *(const float4*)&hds[w][lo * 68 + kt * 32 + hi * 8 + 4];
        float v[8] = {a4.x, a4.y, a4.z, a4.w, b4.x, b4.y, b4.z, b4.w};
        unsigned short sh[8], sm[8], sl[8];
#pragma unroll
        for (int q = 0; q < 8; ++q) {
            unsigned short h = f2bf(v[q]);
            float r1 = v[q] - bf2f(h);
            unsigned short m = f2bf(r1);
            float r2 = r1 - bf2f(m);
            sh[q] = h; sm[q] = m; sl[q] = f2bf(r2);
        }
        short8 ah = *(short8*)sh, am = *(short8*)sm, al = *(short8*)sl;
#pragma unroll
        for (int jt = 0; jt < 4; ++jt) {
            size_t wo = (size_t)kt * 2048 + (jt * 16 + lo) * 32 + hi * 8;
            short8 bh8 = *(const short8*)(w2eh + wo);
            short8 bm8 = *(const short8*)(w2em + wo);
            short8 bl8 = *(const short8*)(w2el + wo);
            f32x4 c = c2[jt];
            c = MF(al, bh8, c);
            c = MF(am, bm8, c);
            c = MF(ah, bl8, c);
            c = MF(am, bh8, c);
            c = MF(ah, bm8, c);
            c = MF(ah, bh8, c);
            c2[jt] = c;
        }
    }
    __syncthreads();    // all hds reads done; safe to overwrite with zls

    // write z_e (f32 global) + bf16 split into LDS zls
#pragma unroll
    for (int jt = 0; jt < 4; ++jt) {
#pragma unroll
        for (int r = 0; r < 4; ++r) {
            float z = c2[jt][r];
            int lrow = w * 16 + hi * 4 + r;
            int col  = jt * 16 + lo;
            zOut[(size_t)(rb + lrow) * LD + col] = z;
            unsigned short hb = f2bf(z);
            zlsH[lrow * 68 + col] = hb;
            zlsL[lrow * 68 + col] = f2bf(z - bf2f(hb));
        }
    }
    __syncthreads();

    // ============================ K2 phase ============================
    short8 bh[4][2], bl[4][2];
#pragma unroll
    for (int g = 0; g < 4; ++g) {
        int lr = g * 16 + lo;
        bh[g][0] = *(const short8*)&zlsH[lr * 68 + hi * 8];
        bh[g][1] = *(const short8*)&zlsH[lr * 68 + 32 + hi * 8];
        bl[g][0] = *(const short8*)&zlsL[lr * 68 + hi * 8];
        bl[g][1] = *(const short8*)&zlsL[lr * 68 + 32 + hi * 8];
    }

    float bb[4], b2v[4];
    f32x4 qv[4];
    int   tt[4];
#pragma unroll
    for (int g = 0; g < 4; ++g) {
        bb[g] = -3.0e38f; b2v[g] = -3.0e38f; tt[g] = 0;
        qv[g][0] = qv[g][1] = qv[g][2] = qv[g][3] = -3.0e38f;
    }

    const int cbase = w * (NEMB / 4);
    const unsigned short* ehp = eh + (size_t)(cbase + lo) * LD + hi * 8;
    const unsigned short* elp = el + (size_t)(cbase + lo) * LD + hi * 8;

    short8 Aa0, Aa1, Aa2, Aa3; f32x4 Ae2;
    short8 Ba0, Ba1, Ba2, Ba3; f32x4 Be2;
    short8 Ca0, Ca1, Ca2, Ca3; f32x4 Ce2;

    K2_LOAD(A, 0);
    K2_LOAD(B, 1);
    K2_LOAD(C, 2);

    for (int tb = 0; tb < 27; tb += 3) {
        K2_COMP(A, tb);     K2_LOAD(A, tb + 3);
        K2_COMP(B, tb + 1); K2_LOAD(B, tb + 4);
        K2_COMP(C, tb + 2); K2_LOAD(C, tb + 5);
    }
    K2_COMP(A, 27); K2_LOAD(A, 30);
    K2_COMP(B, 28); K2_LOAD(B, 31);
    K2_COMP(C, 29);
    K2_COMP(A, 30);
    K2_COMP(B, 31);

    float ss[4];
    int   ii[4];
#pragma unroll
    for (int g = 0; g < 4; ++g) {
        float s0 = qv[g][0], s1 = qv[g][1], s2 = qv[g][2], s3 = qv[g][3];
        float M01 = fmaxf(s0, s1), L01 = fminf(s0, s1);
        float M23 = fmaxf(s2, s3), L23 = fminf(s2, s3);
        int   d01 = (s1 > s0) ? 1 : 0;
        int   d23 = (s3 > s2) ? 3 : 2;
        bool  cp  = (M23 > M01);
        float within2 = fmaxf(fminf(M01, M23), cp ? L23 : L01);
        int   dd  = cp ? d23 : d01;
        ii[g] = cbase + tt[g] * 16 + hi * 4 + dd;
        ss[g] = fmaxf(b2v[g], within2);
    }

#pragma unroll
    for (int off = 16; off <= 32; off <<= 1) {
#pragma unroll
        for (int g = 0; g < 4; ++g) {
            float ob = __shfl_xor(bb[g], off);
            float os = __shfl_xor(ss[g], off);
            int   oi = __shfl_xor(ii[g], off);
            ss[g] = fmaxf(fmaxf(fminf(bb[g], ob), os), ss[g]);
            ii[g] = (ob > bb[g]) ? oi : ii[g];
            bb[g] = fmaxf(bb[g], ob);
        }
    }

    if (lane < 16) {
#pragma unroll
        for (int g = 0; g < 4; ++g) {
            Lb[w][g * 16 + lane] = bb[g];
            Ls[w][g * 16 + lane] = ss[g];
            Li[w][g * 16 + lane] = ii[g];
        }
    }
    __syncthreads();

    if (tid < 64) {
        float B = Lb[0][tid], S = Ls[0][tid];
        int   I = Li[0][tid];
#pragma unroll
        for (int w2 = 1; w2 < 4; ++w2) {
            float ob = Lb[w2][tid], os = Ls[w2][tid];
            int   oi = Li[w2][tid];
            S = fmaxf(fmaxf(fminf(B, ob), os), S);
            I = (ob > B) ? oi : I;
            B = fmaxf(B, ob);
        }
        idx[rb + tid] = I;
        if (B - S < REFINE_THR_Q) {
            int p = atomicAdd(count, 1);
            list[p] = rb + tid;
        }
    }
}

// ---------------------------------------------------------------------------
// K3: exact f64 rescan of flagged near-tie rows (separate launch, proven).
// ---------------------------------------------------------------------------
__global__ __launch_bounds__(256) void k3_refine(const float* __restrict__ z,
                                                 const float* __restrict__ emb,
                                                 const int* __restrict__ count,
                                                 const int* __restrict__ list,
                                                 int* __restrict__ idx) {
    __shared__ double sv[256];
    __shared__ int    sx[256];
    int tid = threadIdx.x;
    int n = *count;
    for (int g = blockIdx.x; g < n; g += gridDim.x) {
        int row = list[g];
        const float4* zr4 = (const float4*)(z + (size_t)row * LD);
        float4 zv[16];
#pragma unroll
        for (int q = 0; q < 16; ++q) zv[q] = zr4[q];

        double best = 1.0e300;
        int bi = NEMB;
#pragma unroll 2
        for (int c = 0; c < 8; ++c) {
            int k = tid * 8 + c;
            const float4* er = (const float4*)(emb + (size_t)k * LD);
            double d0 = 0.0, d1 = 0.0, d2 = 0.0, d3 = 0.0;
#pragma unroll
            for (int q = 0; q < 16; ++q) {
                float4 e4 = er[q];
                double tx = (double)zv[q].x - (double)e4.x;
                double ty = (double)zv[q].y - (double)e4.y;
                double tz = (double)zv[q].z - (double)e4.z;
                double tw = (double)zv[q].w - (double)e4.w;
                d0 += tx * tx; d1 += ty * ty; d2 += tz * tz; d3 += tw * tw;
            }
            double d = (d0 + d1) + (d2 + d3);
            if (d < best) { best = d; bi = k; }
        }
        sv[tid] = best; sx[tid] = bi;
        __syncthreads();
        for (int s = 128; s > 0; s >>= 1) {
            if (tid < s) {
                if (sv[tid + s] < sv[tid] ||
                    (sv[tid + s] == sv[tid] && sx[tid + s] < sx[tid])) {
                    sv[tid] = sv[tid + s]; sx[tid] = sx[tid + s];
                }
            }
            __syncthreads();
        }
        if (tid == 0) idx[row] = sx[0];
        __syncthreads();
    }
}

// ---------------------------------------------------------------------------
// DEC v3 (MFMA split-bf16, 3 terms) — proven rounds 11-19.
// ---------------------------------------------------------------------------
__global__ __launch_bounds__(256, 2) void k_dec(const int* __restrict__ idx,
                                                const float* __restrict__ emb,
                                                const unsigned short* __restrict__ w1h,
                                                const unsigned short* __restrict__ w1l,
                                                const float* __restrict__ b1,
                                                const unsigned short* __restrict__ w2h,
                                                const unsigned short* __restrict__ w2l,
                                                const float* __restrict__ b2,
                                                float* __restrict__ xrec,
                                                float* __restrict__ zq) {
    __shared__ float hds[4][16 * 68];
    int tid  = threadIdx.x;
    int lane = tid & 63;
    int w    = tid >> 6;
    int lo   = lane & 15;
    int hi   = lane >> 4;
    int rb   = blockIdx.x * 64 + w * 16;
    int row  = rb + lo;
    int ix   = idx[row];

    short8 zah[2], zal[2];
    {
        const float* er  = emb + (size_t)ix * LD + hi * 8;
        float* zqr = zq + (size_t)row * LD + hi * 8;
#pragma unroll
        for (int kt = 0; kt < 2; ++kt) {
            float4 a = *(const float4*)(er + kt * 32);
            float4 b = *(const float4*)(er + kt * 32 + 4);
            *(float4*)(zqr + kt * 32) = a;
            *(float4*)(zqr + kt * 32 + 4) = b;
            float v[8] = {a.x, a.y, a.z, a.w, b.x, b.y, b.z, b.w};
            unsigned short hh[8], ll[8];
#pragma unroll
            for (int q = 0; q < 8; ++q) {
                unsigned short hb = f2bf(v[q]);
                hh[q] = hb;
                ll[q] = f2bf(v[q] - bf2f(hb));
            }
            zah[kt] = *(short8*)hh;
            zal[kt] = *(short8*)ll;
        }
    }

#pragma unroll
    for (int jt = 0; jt < 4; ++jt) {
        float bj = b1[jt * 16 + lo];
        f32x4 c = {bj, bj, bj, bj};
#pragma unroll
        for (int kt = 0; kt < 2; ++kt) {
            short8 bh8 = *(const short8*)(w1h + (jt * 16 + lo) * LD + kt * 32 + hi * 8);
            short8 bl8 = *(const short8*)(w1l + (jt * 16 + lo) * LD + kt * 32 + hi * 8);
            c = __builtin_amdgcn_mfma_f32_16x16x32_bf16(zah[kt], bh8, c, 0, 0, 0);
            c = __builtin_amdgcn_mfma_f32_16x16x32_bf16(zah[kt], bl8, c, 0, 0, 0);
            c = __builtin_amdgcn_mfma_f32_16x16x32_bf16(zal[kt], bh8, c, 0, 0, 0);
        }
#pragma unroll
        for (int r = 0; r < 4; ++r)
            hds[w][(hi * 4 + r) * 68 + jt * 16 + lo] = fmaxf(c[r], 0.f);
    }
    __syncthreads();

    short8 hah[2], hal[2];
#pragma unroll
    for (int kt = 0; kt < 2; ++kt) {
        float4 a = *(const float4*)&hds[w][lo * 68 + kt * 32 + hi * 8];
        float4 b = *(const float4*)&hds[w][lo * 68 + kt * 32 + hi * 8 + 4];
        float v[8] = {a.x, a.y, a.z, a.w, b.x, b.y, b.z, b.w};
        unsigned short hh[8], ll[8];
#pragma unroll
        for (int q = 0; q < 8; ++q) {
            unsigned short hb = f2bf(v[q]);
            hh[q] = hb;
            ll[q] = f2bf(v[q] - bf2f(hb));
        }
        hah[kt] = *(short8*)hh;
        hal[kt] = *(short8*)ll;
    }

    for (int jt = 0; jt < 16; ++jt) {
        float bj = b2[jt * 16 + lo];
        f32x4 c = {bj, bj, bj, bj};
#pragma unroll
        for (int kt = 0; kt < 2; ++kt) {
            short8 bh8 = *(const short8*)(w2h + (jt * 16 + lo) * LD + kt * 32 + hi * 8);
            short8 bl8 = *(const short8*)(w2l + (jt * 16 + lo) * LD + kt * 32 + hi * 8);
            c = __builtin_amdgcn_mfma_f32_16x16x32_bf16(hah[kt], bh8, c, 0, 0, 0);
            c = __builtin_amdgcn_mfma_f32_16x16x32_bf16(hah[kt], bl8, c, 0, 0, 0);
            c = __builtin_amdgcn_mfma_f32_16x16x32_bf16(hal[kt], bh8, c, 0, 0, 0);
        }
#pragma unroll
        for (int r = 0; r < 4; ++r)
            xrec[(size_t)(rb + hi * 4 + r) * SD + jt * 16 + lo] = c[r];
    }
}

// ---------------------------------------------------------------------------
extern "C" void kernel_launch(void* const* d_in, const int* in_sizes, int n_in,
                              void* d_out, int out_size, void* d_ws, size_t ws_size,
                              hipStream_t stream) {
    const float* x   = (const float*)d_in[0];
    const float* ew1 = (const float*)d_in[1];
    const float* eb1 = (const float*)d_in[2];
    const float* ew2 = (const float*)d_in[3];
    const float* eb2 = (const float*)d_in[4];
    const float* emb = (const float*)d_in[5];
    const float* dw1 = (const float*)d_in[6];
    const float* db1 = (const float*)d_in[7];
    const float* dw2 = (const float*)d_in[8];
    const float* db2 = (const float*)d_in[9];

    float* out  = (float*)d_out;
    float* xrec = out;                               // [B,256] (written LAST)
    float* zE   = out + (size_t)BATCH * SD;          // [B,64]
    float* zQ   = zE + (size_t)BATCH * LD;           // [B,64]

    // transient scratch inside the x_recon region (dead once k_dec writes):
    char* xb = (char*)xrec;
    unsigned short* eh   = (unsigned short*)(xb + (8u << 20));         // 256 KB
    unsigned short* el   = (unsigned short*)(xb + (8u << 20) + (NEMB * LD * 2)); // 256 KB
    float*          e2q  = (float*)(xb + (9u << 20));                  // 8 KB
    unsigned short* w1eh = (unsigned short*)(xb + (10u << 20));        // 32 KB
    unsigned short* w1em = w1eh + 16384;                               // 32 KB
    unsigned short* w1el = w1em + 16384;                               // 32 KB
    unsigned short* w2eh = w1el + 16384;                               // 8 KB
    unsigned short* w2em = w2eh + 4096;                                // 8 KB
    unsigned short* w2el = w2em + 4096;                                // 8 KB

    char* ws = (char*)d_ws;
    int*  count = (int*)ws;                                     // 4 B
    int*  idxA  = (int*)(ws + 16384);                           // 128 KB
    int*  list  = (int*)(ws + 147456);                          // 128 KB
    unsigned short* w1h = (unsigned short*)(ws + 278528);       // 8 KB
    unsigned short* w1l = (unsigned short*)(ws + 286720);       // 8 KB
    unsigned short* w2h = (unsigned short*)(ws + 294912);       // 32 KB
    unsigned short* w2l = (unsigned short*)(ws + 327680);       // 32 KB

    hipLaunchKernelGGL(k0_all,    dim3(168),        dim3(256), 0, stream,
                       emb, dw1, dw2, ew1, ew2, e2q, eh, el,
                       w1h, w1l, w2h, w2l, w1eh, w1em, w1el, w2eh, w2em, w2el, count);
    hipLaunchKernelGGL(k_fused,   dim3(BATCH / 64), dim3(256), 0, stream,
                       x, w1eh, w1em, w1el, eb1, w2eh, w2em, w2el, eb2,
                       eh, el, e2q, zE, idxA, list, count);
    hipLaunchKernelGGL(k3_refine, dim3(128),        dim3(256), 0, stream,
                       zE, emb, count, list, idxA);
    hipLaunchKernelGGL(k_dec,     dim3(BATCH / 64), dim3(256), 0, stream,
                       idxA, emb, w1h, w1l, db1, w2h, w2l, db2, xrec, zQ);
}